// Round 9
// baseline (157.584 us; speedup 1.0000x reference)
//
#include <hip/hip_runtime.h>
#include <hip/hip_bf16.h>
#include <hip/hip_fp16.h>

// deepSNN forward, layer_idx=3 path, element-sparse conv2.
// x:(20,6,160,160) w1:(30,6,4,4) w2:(250,30,3,3) w3:(200,250,3,3)
// pipeline: pad2->conv1->fire(1)->pool2x2 -> pad2->conv2->fire(1)->pool3x3
//           -> pad2->conv3->fire(25) -> out = [spk | pot] (2 x 20*200*29*29 fp32)
//
// r27: MEASUREMENT ROUND #2. r26 landed conv2's pk_add+sentinel at -5.1us
// (115.2 total) -- real but far below the predicted -18..-22, so conv2 is
// not VALU-throughput-bound. Ledger (r23 identity): conv2+conv3+gaps =
// 124.9 - 44.5 fill - 15.7 conv1m = 64.7us -> conv2 plausibly 40-50us, the
// dominant controllable item, but unmeasured. k_conv2 is launched 3x
// (idempotent: pool2m/flags2 rewritten with identical values):
//   conv2 ~= (total - 115.2) / 2   [duplicates removed next round]
// Decision rule r28: conv2>=25 -> rebuild dense-MFMA conv2 with full-width
// A-build + swizzled LDS (r22's +9.6 regression is consistent with sparse
// conv2 being ~45, not ~36); conv2<=15 -> attack gaps/fusion instead.
// r25/r26: conv2 v_pk_add_f16 + zero-sentinel (unconditional adds).
// r24: conv1m LDS-staged (15.7 -> ~11us). r19: conv1 bf16 MFMA.

#define OUT_HALF 3364000  // 20*200*29*29
#define MASK_PLANE 128000 // 20*80*80 (u32 elements per plane)
#define T_FLOATS 168200   // 200*29*29 floats per t per half

typedef float f32x16 __attribute__((ext_vector_type(16)));
typedef short bf8s __attribute__((ext_vector_type(8)));
typedef float f32x4 __attribute__((ext_vector_type(4)));
typedef f32x4 f32x4u __attribute__((aligned(4)));  // 4B-aligned vec4 load

// HW packed f32->bf16 RTE: dst.lo16 = bf16(a), dst.hi16 = bf16(b).
static __device__ __forceinline__ unsigned int cvtpk(float a, float b) {
    unsigned int r;
    asm("v_cvt_pk_bf16_f32 %0, %1, %2" : "=v"(r) : "v"(a), "v"(b));
    return r;
}
static __device__ __forceinline__ unsigned short bfbits(float a) {
    union { __hip_bfloat16 h; unsigned short u; } cv;
    cv.h = __float2bfloat16(a);
    return cv.u;
}
static __device__ __forceinline__ __half2 bch2(unsigned int u) {
    union { unsigned int u32; __half2 h2; } cv; cv.u32 = u;
    return cv.h2;
}
// interleave: bit k of v -> bit 2k
static __device__ __forceinline__ unsigned long long expand32(unsigned int v) {
    unsigned long long x = v;
    x = (x | (x << 16)) & 0x0000FFFF0000FFFFull;
    x = (x | (x << 8))  & 0x00FF00FF00FF00FFull;
    x = (x | (x << 4))  & 0x0F0F0F0F0F0F0F0Full;
    x = (x | (x << 2))  & 0x3333333333333333ull;
    x = (x | (x << 1))  & 0x5555555555555555ull;
    return x;
}

// ---------------- conv1 (bf16 MFMA, LDS-staged) + fire(1) + pool2x2 -> mask1
//                  blocks 0..1599: conv1 (t=b/80, pr=b%80), 320 thr, 5 waves
//                  blocks 1600..1711: w2h pack (+ zero sentinel pad) + flags2
// LDS xs[ch][copy][row][84] u32: row = local src row 0..4 (global 2pr-2+row),
//   copy0 (E) pair p = src cols (2p-2, 2p-1); copy1 (O) pair k = (2k-1, 2k).
//   OOB staged as 0. Wave wv = jblk: output rows 2pr (acc0), 2pr+1 (acc1),
//   cols j=32wv+m. Lane (m=l&31, hi=l>>5): A-frag rows local 2hi+{0,1,2},
//   cols j-2..j+1 = pairs a, a+1 of copy (j&1), a = j>>1.
// C/D: col(oc)=lane&31, row(j-idx)=(reg&3)+8*(reg>>2)+4*hi  [verified map]
__global__ __launch_bounds__(320) void k_conv1m(const float* __restrict__ x,
                                                const float* __restrict__ w1,
                                                const float* __restrict__ w2,
                                                unsigned int* __restrict__ w2h,
                                                unsigned int* __restrict__ mask1,
                                                unsigned int* __restrict__ flags2) {
    int tid = threadIdx.x;
    if (blockIdx.x >= 1600) {  // w2h[ck*128+pl] = pack(w2[2pl][ck], w2[2pl+1][ck])
        int tb = blockIdx.x - 1600;
        if (tb == 0)
            for (int i = tid; i < 540; i += 320) flags2[i] = 0u;
        int idx = tb * 320 + tid;  // < 112*320 = 35840
        if (idx < 35712) {         // [34560,35712) = zero sentinel region (c=30)
            unsigned int val = 0u;
            if (idx < 34560) {
                int ck = idx >> 7, pl = idx & 127;
                int oc0 = 2 * pl, oc1 = oc0 + 1;
                float a = (oc0 < 250) ? w2[oc0 * 270 + ck] : 0.f;
                float bb = (oc1 < 250) ? w2[oc1 * 270 + ck] : 0.f;
                union { __half2 h2; unsigned int u; } cv;
                cv.h2.x = __float2half(a);
                cv.h2.y = __float2half(bb);
                val = cv.u;
            }
            w2h[idx] = val;
        }
        return;
    }

    __shared__ unsigned int xs[6 * 10 * 84];      // 20160 B  [ch][copy*5+row][84]
    __shared__ unsigned short B_lds[6 * 64 * 8];  // 6144 B, frag-linear

    int b = blockIdx.x;
    int pr = b % 80, t = b / 80;

    // ---- stage B fragments (w1 -> bf16, frag-linear)
    for (int q = tid; q < 3072; q += 320) {
        int i = q & 7, ll = (q >> 3) & 63, ks = q >> 9;
        int oc = ll & 31;
        int kg = ks * 16 + ((ll >> 5) << 3) + i;
        float w = (oc < 30) ? w1[oc * 96 + kg] : 0.f;
        B_lds[q] = bfbits(w);
    }

    // ---- stage x tile: rows 2pr-2..2pr+2, cols -2..161, 6 ch, E+O copies
    if (tid < 30) {
        int ch = tid / 5, r = tid % 5;
        int sr = 2 * pr - 2 + r;
        float x0 = ((unsigned)sr < 160u) ? x[((t * 6 + ch) * 160 + sr) * 160] : 0.f;
        xs[(ch * 10 + r) * 84] = 0u;
        xs[(ch * 10 + 5 + r) * 84] = cvtpk(0.f, x0);
    }
    // main pairs: unit u = (ch,row)*40 + q; float4 = src cols 4q..4q+3
#pragma unroll
    for (int n = 0; n < 4; ++n) {
        int u = n * 320 + tid;
        if (u >= 1200) break;
        int q = u % 40, combo = u / 40;
        int ch = combo / 5, r = combo % 5;
        int sr = 2 * pr - 2 + r;
        const float* xp = x + ((t * 6 + ch) * 160 + sr) * 160;
        f32x4 f; f.x = 0.f; f.y = 0.f; f.z = 0.f; f.w = 0.f;
        bool inr = (unsigned)sr < 160u;
        if (inr) f = *(const f32x4u*)(xp + 4 * q);
        float nx = __shfl_down(f.x, 1);           // neighbor's col 4q+4
        if ((tid & 63) == 63 && q != 39)          // cross-wave neighbor
            nx = inr ? xp[4 * q + 4] : 0.f;
        if (q == 39) nx = 0.f;                    // col 160 is padding
        unsigned int e0 = cvtpk(f.x, f.y), e1 = cvtpk(f.z, f.w);
        unsigned int o0 = cvtpk(f.y, f.z), o1 = cvtpk(f.w, nx);
        unsigned int baseE = (unsigned)(ch * 10 + r) * 84 + 2 * q + 1;
        unsigned int baseO = (unsigned)(ch * 10 + 5 + r) * 84 + 2 * q + 1;
        xs[baseE] = e0; xs[baseE + 1] = e1;
        xs[baseO] = o0; xs[baseO + 1] = o1;
    }
    __syncthreads();

    int l = tid & 63, wv = tid >> 6;
    int m = l & 31, hi = l >> 5;
    int j = wv * 32 + m;
    int a = j >> 1, par = j & 1;

    bf8s bq[6];
#pragma unroll
    for (int ks = 0; ks < 6; ++ks)
        bq[ks] = *(const bf8s*)&B_lds[(ks * 64 + l) * 8];

    f32x16 acc0 = (f32x16)(0.0f);
    f32x16 acc1 = (f32x16)(0.0f);
    unsigned int bidx0 = (unsigned)(par * 5 + 2 * hi) * 84 + a;

#pragma unroll
    for (int ks = 0; ks < 6; ++ks) {
        unsigned int bidx = bidx0 + (unsigned)ks * 840;
        unsigned int r00 = xs[bidx],       r01 = xs[bidx + 1];
        unsigned int r10 = xs[bidx + 84],  r11 = xs[bidx + 85];
        unsigned int r20 = xs[bidx + 168], r21 = xs[bidx + 169];
        union { bf8s s; unsigned int u4[4]; } a0, a1;
        a0.u4[0] = r00; a0.u4[1] = r01; a0.u4[2] = r10; a0.u4[3] = r11;
        a1.u4[0] = r10; a1.u4[1] = r11; a1.u4[2] = r20; a1.u4[3] = r21;
        acc0 = __builtin_amdgcn_mfma_f32_32x32x16_bf16(a0.s, bq[ks], acc0, 0, 0, 0);
        acc1 = __builtin_amdgcn_mfma_f32_32x32x16_bf16(a1.s, bq[ks], acc1, 0, 0, 0);
    }

    // fire(>1) + pool2x2 + pack 30 oc bits -> 3 mask planes of 10 bits
    unsigned int mbase = (unsigned int)((t * 80 + pr) * 80 + wv * 16);
#pragma unroll
    for (int aa = 0; aa < 8; ++aa) {
        bool s = acc0[2 * aa] > 1.f || acc0[2 * aa + 1] > 1.f ||
                 acc1[2 * aa] > 1.f || acc1[2 * aa + 1] > 1.f;
        unsigned long long bal = __ballot(s);
        if (l < 6) {
            int h = l >> 1;
            unsigned int word = (l & 1) ? (unsigned int)(bal >> 32)
                                        : (unsigned int)bal;
            int pc = (aa & 1) + ((aa >> 1) << 2) + ((l & 1) << 1);
            mask1[h * MASK_PLANE + mbase + pc] = (word >> (10 * h)) & 0x3FFu;
        }
    }
}

// ---------------- sparse conv2(3x3) + fire(1.0) + pool3x3 -> pool2m ballot
// block: (t, ph, 9 pw-ninths) = 4860 blocks, 256 thr = 4 waves.
// fp16 oc-pair weights: lane l of oc-half h owns ocs h*128+2l, h*128+2l+1;
// one u32 load = 128 ocs. Wave (h = wv&1, grp = wv>>1): grp0 walks windows
// (pwA, pwA+1) fused; grp1 walks pwA+2 solo (dual-spike).
// v_pk_add_f16 accumulation, UNCONDITIONAL adds: exhausted masks yield
// channel 30 (ctz of the 0x40000000 sentinel) whose w2h rows are zero.
__global__ __launch_bounds__(256) void k_conv2(const unsigned int* __restrict__ mask1,
                                               const unsigned int* __restrict__ w2h,
                                               unsigned long long* __restrict__ pool2m,
                                               unsigned int* __restrict__ flags2) {
    __shared__ unsigned int m_lds[5 * 84];  // rows 3ph-2..3ph+2, cols -2..81

    int b = blockIdx.x;
    int ninth = b % 9;  b /= 9;
    int ph = b % 27;
    int t = b / 27;
    int tid = threadIdx.x;
    int l = tid & 63, wv = tid >> 6;
    int h = wv & 1, grp = wv >> 1;
    int r0 = 3 * ph - 2;
    int pwA = ninth * 3;

    for (int idx = tid; idx < 420; idx += 256) {
        int r = idx / 84, col = idx % 84;
        int gr = r0 + r, gc = col - 2;
        unsigned int v = 0;
        if ((unsigned)gr < 80u && (unsigned)gc < 80u) {
            int i2 = (t * 80 + gr) * 80 + gc;
            v = mask1[i2] | (mask1[MASK_PLANE + i2] << 10) |
                (mask1[2 * MASK_PLANE + i2] << 20);
        }
        m_lds[idx] = v;
    }
    __syncthreads();

    const unsigned int* wb = w2h + h * 64 + l;  // [ck][pl] stride 128
    unsigned long long* prow = pool2m + ((t * 27 + ph) * 27) * 4 + 2 * h;
    __half2 zh = bch2(0u);

    if (grp == 0) {
        // ---- pw pair (pwA, pwA+1): fused walk, unconditional pk_add ----
        int c0A = 3 * pwA, c0B = c0A + 3;
        unsigned int qA[25], qB[25];
#pragma unroll
        for (int dr = 0; dr < 5; ++dr)
#pragma unroll
            for (int ds = 0; ds < 5; ++ds) {
                qA[dr * 5 + ds] = m_lds[dr * 84 + c0A + ds];
                qB[dr * 5 + ds] = m_lds[dr * 84 + c0B + ds];
            }

        __half2 accA[3][3], accB[3][3];
#pragma unroll
        for (int i = 0; i < 3; ++i)
#pragma unroll
            for (int j = 0; j < 3; ++j) { accA[i][j] = zh; accB[i][j] = zh; }

#pragma unroll
        for (int dr = 0; dr < 5; ++dr) {
#pragma unroll
            for (int ds = 0; ds < 5; ++ds) {
                unsigned int mA = qA[dr * 5 + ds];
                unsigned int mB = qB[dr * 5 + ds];
                while (mA | mB) {  // wave-uniform
                    int cA = __builtin_ctz(mA | 0x40000000u);  // empty -> 30
                    int cB = __builtin_ctz(mB | 0x40000000u);
                    mA &= mA - 1;  // 0 stays 0
                    mB &= mB - 1;
                    const unsigned int* pA = wb + cA * 1152;  // c stride 9*128
                    const unsigned int* pB = wb + cB * 1152;
                    unsigned int uA[3][3], uB[3][3];
#pragma unroll
                    for (int i = 0; i < 3; ++i) {
                        if (dr - i < 0 || dr - i > 2) continue;
#pragma unroll
                        for (int j = 0; j < 3; ++j) {
                            if (ds - j < 0 || ds - j > 2) continue;
                            int off = ((dr - i) * 3 + (ds - j)) * 128;
                            uA[i][j] = pA[off];
                            uB[i][j] = pB[off];
                        }
                    }
#pragma unroll
                    for (int i = 0; i < 3; ++i) {
                        if (dr - i < 0 || dr - i > 2) continue;
#pragma unroll
                        for (int j = 0; j < 3; ++j) {
                            if (ds - j < 0 || ds - j > 2) continue;
                            accA[i][j] = __hadd2(accA[i][j], bch2(uA[i][j]));
                            accB[i][j] = __hadd2(accB[i][j], bch2(uB[i][j]));
                        }
                    }
                }
            }
        }

        bool sA0 = false, sA1 = false, sB0 = false, sB1 = false;
#pragma unroll
        for (int i = 0; i < 3; ++i)
#pragma unroll
            for (int j = 0; j < 3; ++j) {
                sA0 = sA0 || (__low2float(accA[i][j])  > 1.f);
                sA1 = sA1 || (__high2float(accA[i][j]) > 1.f);
                sB0 = sB0 || (__low2float(accB[i][j])  > 1.f);
                sB1 = sB1 || (__high2float(accB[i][j]) > 1.f);
            }
        unsigned long long bA0 = __ballot(sA0), bA1 = __ballot(sA1);
        unsigned long long bB0 = __ballot(sB0), bB1 = __ballot(sB1);
        unsigned long long wA0 = expand32((unsigned int)bA0) |
                                 (expand32((unsigned int)bA1) << 1);
        unsigned long long wA1 = expand32((unsigned int)(bA0 >> 32)) |
                                 (expand32((unsigned int)(bA1 >> 32)) << 1);
        unsigned long long wB0 = expand32((unsigned int)bB0) |
                                 (expand32((unsigned int)bB1) << 1);
        unsigned long long wB1 = expand32((unsigned int)(bB0 >> 32)) |
                                 (expand32((unsigned int)(bB1 >> 32)) << 1);
        if (l == 0) {
            prow[pwA * 4]           = wA0;
            prow[pwA * 4 + 1]       = wA1;
            prow[(pwA + 1) * 4]     = wB0;
            prow[(pwA + 1) * 4 + 1] = wB1;
        }
        if ((wA0 | wA1 | wB0 | wB1) && l == 0)
            flags2[t * 27 + ph] = 1u;  // same-value multi-writer
    } else {
        // ---- solo pw (pwA+2), dual-spike walk, unconditional pk_add ----
        int pw = pwA + 2;
        int c0 = 3 * pw;
        unsigned int q[25];
#pragma unroll
        for (int dr = 0; dr < 5; ++dr)
#pragma unroll
            for (int ds = 0; ds < 5; ++ds)
                q[dr * 5 + ds] = m_lds[dr * 84 + c0 + ds];

        __half2 acc[3][3];
#pragma unroll
        for (int i = 0; i < 3; ++i)
#pragma unroll
            for (int j = 0; j < 3; ++j) acc[i][j] = zh;

#pragma unroll
        for (int dr = 0; dr < 5; ++dr) {
#pragma unroll
            for (int ds = 0; ds < 5; ++ds) {
                unsigned int m = q[dr * 5 + ds];
                while (m) {  // wave-uniform
                    int c1 = __builtin_ctz(m); m &= m - 1;
                    int c2 = m ? __builtin_ctz(m) : 30;  // empty -> zero row
                    m &= m - 1;  // 0 stays 0
                    const unsigned int* p1 = wb + c1 * 1152;
                    const unsigned int* p2 = wb + c2 * 1152;
                    unsigned int u1[3][3], u2[3][3];
#pragma unroll
                    for (int i = 0; i < 3; ++i) {
                        if (dr - i < 0 || dr - i > 2) continue;
#pragma unroll
                        for (int j = 0; j < 3; ++j) {
                            if (ds - j < 0 || ds - j > 2) continue;
                            int off = ((dr - i) * 3 + (ds - j)) * 128;
                            u1[i][j] = p1[off];
                            u2[i][j] = p2[off];
                        }
                    }
#pragma unroll
                    for (int i = 0; i < 3; ++i) {
                        if (dr - i < 0 || dr - i > 2) continue;
#pragma unroll
                        for (int j = 0; j < 3; ++j) {
                            if (ds - j < 0 || ds - j > 2) continue;
                            acc[i][j] = __hadd2(acc[i][j], bch2(u1[i][j]));
                            acc[i][j] = __hadd2(acc[i][j], bch2(u2[i][j]));
                        }
                    }
                }
            }
        }

        bool s0 = false, s1 = false;
#pragma unroll
        for (int i = 0; i < 3; ++i)
#pragma unroll
            for (int j = 0; j < 3; ++j) {
                s0 = s0 || (__low2float(acc[i][j])  > 1.f);
                s1 = s1 || (__high2float(acc[i][j]) > 1.f);
            }
        unsigned long long b0 = __ballot(s0), b1 = __ballot(s1);
        unsigned long long w0 = expand32((unsigned int)b0) |
                                (expand32((unsigned int)b1) << 1);
        unsigned long long w1 = expand32((unsigned int)(b0 >> 32)) |
                                (expand32((unsigned int)(b1 >> 32)) << 1);
        if (l == 0) {
            prow[pw * 4]     = w0;
            prow[pw * 4 + 1] = w1;
        }
        if ((w0 | w1) && l == 0) flags2[t * 27 + ph] = 1u;
    }
}

// ---------------- conv3(3x3) + fire(25.0) -> out [spk|pot] (20,200,29,29) x2
__global__ __launch_bounds__(320) void k_conv3(const unsigned long long* __restrict__ pool2m,
                                               const float* __restrict__ w3,
                                               float* __restrict__ out,
                                               const unsigned int* __restrict__ flags2) {
    __shared__ float w_lds[25 * 9 * 40];   // 9000 floats, [ck_local][ocl]
    __shared__ float in_lds[25 * 4 * 34];  // 3400 floats, [cl][r][col]

    int b = blockIdx.x;
    int rb = b % 15;  b /= 15;
    int ocg = b % 5;  b /= 5;
    int t = b;
    int oc0 = ocg * 40;
    int r0 = 2 * rb;  // output rows r0, r0+1
    int tid = threadIdx.x;
    int ocl = tid % 40, ct = tid / 40;  // ct in [0,8)

    // whole-t union of flags (wave-uniform scalar loads)
    {
        unsigned int fT = 0;
        const unsigned int* fp = flags2 + t * 27;
#pragma unroll
        for (int r = 0; r < 27; ++r) fT |= fp[r];
        if (fT == 0) {
            float4 z; z.x = 0.f; z.y = 0.f; z.z = 0.f; z.w = 0.f;
            float4* o0 = (float4*)(out + (size_t)t * T_FLOATS);
            float4* o1 = (float4*)(out + OUT_HALF + (size_t)t * T_FLOATS);
            int s = ocg * 15 + rb;           // slice id 0..74
            int lo = s * 561;                // 75*561 = 42075 >= 42050
            int hi = lo + 561; if (hi > 42050) hi = 42050;
            for (int i = lo + tid; i < hi; i += 320) {
                o0[i] = z;
                o1[i] = z;
            }
            return;
        }
    }

    // receptive field: pool2 rows r0-2..r0+1
    {
        unsigned int f = 0;
        int rlo = r0 - 2; if (rlo < 0) rlo = 0;
        int rhi = r0 + 1; if (rhi > 26) rhi = 26;
        for (int r = rlo; r <= rhi; ++r) f |= flags2[t * 27 + r];
        if (f == 0) {
            int nrows = (r0 + 1 < 29) ? 2 : 1;
            int stride = 29 * nrows;
            int cnt = 40 * stride;
            for (int idx = tid; idx < cnt; idx += 320) {
                int o = idx / stride, rem = idx % stride;
                size_t base = (size_t)((t * 200 + oc0 + o) * 29 + r0) * 29 + rem;
                out[base] = 0.f;
                out[OUT_HALF + base] = 0.f;
            }
            return;
        }
    }

    float acc[2][4];
#pragma unroll
    for (int i = 0; i < 2; ++i)
#pragma unroll
        for (int j = 0; j < 4; ++j) acc[i][j] = 0.f;

    for (int chn = 0; chn < 10; ++chn) {  // channel chunks of 25
        int cc0 = chn * 25;
        for (int idx = tid; idx < 25 * 9 * 40; idx += 320) {
            int o = idx % 40, ck = idx / 40;         // ck in [0,225)
            int ckg = cc0 * 9 + ck;                  // global (c,kh,kw) index
            w_lds[idx] = w3[(size_t)(oc0 + o) * 2250 + ckg];
        }
        for (int idx = tid; idx < 25 * 4 * 34; idx += 320) {
            int col = idx % 34;
            int rem = idx / 34;
            int r = rem & 3, cl = rem >> 2;
            int gr = r0 + r - 2, gc = col - 2;
            float v = 0.f;
            if ((unsigned)gr < 27u && (unsigned)gc < 27u) {
                int c = cc0 + cl;
                unsigned long long wbits =
                    pool2m[((t * 27 + gr) * 27 + gc) * 4 + (c >> 6)];
                v = (float)((wbits >> (c & 63)) & 1ull);
            }
            in_lds[idx] = v;
        }
        __syncthreads();

        for (int cl = 0; cl < 25; ++cl) {
            float in[4][6];
#pragma unroll
            for (int r = 0; r < 4; ++r)
#pragma unroll
                for (int j = 0; j < 6; ++j)
                    in[r][j] = in_lds[(cl * 4 + r) * 34 + ct * 4 + j];
            const float* wp = &w_lds[cl * 360 + ocl];
#pragma unroll
            for (int k = 0; k < 9; ++k) {
                float w = wp[k * 40];
                int kh = k / 3, kw = k % 3;
#pragma unroll
                for (int i = 0; i < 2; ++i)
#pragma unroll
                    for (int j = 0; j < 4; ++j)
                        acc[i][j] += in[i + kh][j + kw] * w;
            }
        }
        __syncthreads();
    }

    {
        int oc = oc0 + ocl;  // always < 200
#pragma unroll
        for (int i = 0; i < 2; ++i) {
            int r = r0 + i;
            if (r < 29) {
#pragma unroll
                for (int j = 0; j < 4; ++j) {
                    int col = ct * 4 + j;
                    if (col < 29) {
                        float pot = acc[i][j];
                        bool s = pot > 25.f;
                        size_t base = ((size_t)((t * 200 + oc) * 29 + r)) * 29 + col;
                        out[base] = s ? 1.f : 0.f;
                        out[OUT_HALF + base] = s ? pot : 0.f;
                    }
                }
            }
        }
    }
}

extern "C" void kernel_launch(void* const* d_in, const int* in_sizes, int n_in,
                              void* d_out, int out_size, void* d_ws, size_t ws_size,
                              hipStream_t stream) {
    const float* x  = (const float*)d_in[0];
    const float* w1 = (const float*)d_in[1];
    const float* w2 = (const float*)d_in[2];
    const float* w3 = (const float*)d_in[3];
    float* out = (float*)d_out;

    // workspace layout (bytes):
    //   mask1  u32: [0, 1,536,000)           3 planes x 20*80*80
    //   pool2m u64: [1,536,000, 2,002,560)   20*27*27*4 x 8B ballot words
    //   w2h    u32: [2,002,560, 2,145,408)   270x128 fp16 pairs + zero pad
    //   flags2    : [2,277,376, +2,160)      u32[20*27]
    unsigned int* mask1 = (unsigned int*)d_ws;
    unsigned long long* pool2m = (unsigned long long*)((char*)d_ws + 1536000);
    unsigned int* w2h = (unsigned int*)((char*)d_ws + 2002560);
    unsigned int* flags2 = (unsigned int*)((char*)d_ws + 2277376);

    // blocks 0..1599: conv1 (LDS-staged MFMA); 1600..1711: w2h pack + flags2
    k_conv1m<<<1712, 320, 0, stream>>>(x, w1, w2, w2h, mask1, flags2);
    // MEASUREMENT: k_conv2 launched 3x (idempotent -- pool2m/flags2 get
    // identical values each run). conv2 ~= (total - 115.2)/2.
    k_conv2<<<20 * 27 * 9, 256, 0, stream>>>(mask1, w2h, pool2m, flags2);
    k_conv2<<<20 * 27 * 9, 256, 0, stream>>>(mask1, w2h, pool2m, flags2);
    k_conv2<<<20 * 27 * 9, 256, 0, stream>>>(mask1, w2h, pool2m, flags2);
    k_conv3<<<20 * 5 * 15, 320, 0, stream>>>(pool2m, w3, out, flags2);
}

// Round 10
// 126.798 us; speedup vs baseline: 1.2428x; 1.2428x over previous
//
#include <hip/hip_runtime.h>
#include <hip/hip_bf16.h>
#include <hip/hip_fp16.h>

// deepSNN forward, layer_idx=3 path, element-sparse conv2.
// x:(20,6,160,160) w1:(30,6,4,4) w2:(250,30,3,3) w3:(200,250,3,3)
// pipeline: pad2->conv1->fire(1)->pool2x2 -> pad2->conv2->fire(1)->pool3x3
//           -> pad2->conv3->fire(25) -> out = [spk | pot] (2 x 20*200*29*29 fp32)
//
// r28: MEASUREMENT ROUND #3. r27 measured conv2 = 21.2us/launch (3x-launch
// delta). Ledger: fill 44 + conv1m 11 + conv2 21.2 + conv3(model 6) = 82 of
// 115.2 -> ~33us unaccounted: either conv3 >> model, or per-dispatch
// overhead ~8-10us/node. These imply opposite next moves (attack conv3 vs
// cut dispatch count via cooperative fusion). k_conv3 launched 3x
// (idempotent: out rewritten with identical values):
//   conv3+gap ~= (total - 115.2) / 2   [duplicates removed next round]
// Decision rule r29: conv3 <= 10 -> gaps ~25us -> fuse/reduce dispatches;
// conv3 >= 15 -> conv3 mispriced -> attack conv3 directly.
// r25/r26: conv2 v_pk_add_f16 + zero-sentinel. r24: conv1m LDS-staged.
// r23: conv1m = 15.7us measured. r19: conv1 bf16 MFMA implicit GEMM.

#define OUT_HALF 3364000  // 20*200*29*29
#define MASK_PLANE 128000 // 20*80*80 (u32 elements per plane)
#define T_FLOATS 168200   // 200*29*29 floats per t per half

typedef float f32x16 __attribute__((ext_vector_type(16)));
typedef short bf8s __attribute__((ext_vector_type(8)));
typedef float f32x4 __attribute__((ext_vector_type(4)));
typedef f32x4 f32x4u __attribute__((aligned(4)));  // 4B-aligned vec4 load

// HW packed f32->bf16 RTE: dst.lo16 = bf16(a), dst.hi16 = bf16(b).
static __device__ __forceinline__ unsigned int cvtpk(float a, float b) {
    unsigned int r;
    asm("v_cvt_pk_bf16_f32 %0, %1, %2" : "=v"(r) : "v"(a), "v"(b));
    return r;
}
static __device__ __forceinline__ unsigned short bfbits(float a) {
    union { __hip_bfloat16 h; unsigned short u; } cv;
    cv.h = __float2bfloat16(a);
    return cv.u;
}
static __device__ __forceinline__ __half2 bch2(unsigned int u) {
    union { unsigned int u32; __half2 h2; } cv; cv.u32 = u;
    return cv.h2;
}
// interleave: bit k of v -> bit 2k
static __device__ __forceinline__ unsigned long long expand32(unsigned int v) {
    unsigned long long x = v;
    x = (x | (x << 16)) & 0x0000FFFF0000FFFFull;
    x = (x | (x << 8))  & 0x00FF00FF00FF00FFull;
    x = (x | (x << 4))  & 0x0F0F0F0F0F0F0F0Full;
    x = (x | (x << 2))  & 0x3333333333333333ull;
    x = (x | (x << 1))  & 0x5555555555555555ull;
    return x;
}

// ---------------- conv1 (bf16 MFMA, LDS-staged) + fire(1) + pool2x2 -> mask1
//                  blocks 0..1599: conv1 (t=b/80, pr=b%80), 320 thr, 5 waves
//                  blocks 1600..1711: w2h pack (+ zero sentinel pad) + flags2
// LDS xs[ch][copy][row][84] u32: row = local src row 0..4 (global 2pr-2+row),
//   copy0 (E) pair p = src cols (2p-2, 2p-1); copy1 (O) pair k = (2k-1, 2k).
//   OOB staged as 0. Wave wv = jblk: output rows 2pr (acc0), 2pr+1 (acc1),
//   cols j=32wv+m. Lane (m=l&31, hi=l>>5): A-frag rows local 2hi+{0,1,2},
//   cols j-2..j+1 = pairs a, a+1 of copy (j&1), a = j>>1.
// C/D: col(oc)=lane&31, row(j-idx)=(reg&3)+8*(reg>>2)+4*hi  [verified map]
__global__ __launch_bounds__(320) void k_conv1m(const float* __restrict__ x,
                                                const float* __restrict__ w1,
                                                const float* __restrict__ w2,
                                                unsigned int* __restrict__ w2h,
                                                unsigned int* __restrict__ mask1,
                                                unsigned int* __restrict__ flags2) {
    int tid = threadIdx.x;
    if (blockIdx.x >= 1600) {  // w2h[ck*128+pl] = pack(w2[2pl][ck], w2[2pl+1][ck])
        int tb = blockIdx.x - 1600;
        if (tb == 0)
            for (int i = tid; i < 540; i += 320) flags2[i] = 0u;
        int idx = tb * 320 + tid;  // < 112*320 = 35840
        if (idx < 35712) {         // [34560,35712) = zero sentinel region (c=30)
            unsigned int val = 0u;
            if (idx < 34560) {
                int ck = idx >> 7, pl = idx & 127;
                int oc0 = 2 * pl, oc1 = oc0 + 1;
                float a = (oc0 < 250) ? w2[oc0 * 270 + ck] : 0.f;
                float bb = (oc1 < 250) ? w2[oc1 * 270 + ck] : 0.f;
                union { __half2 h2; unsigned int u; } cv;
                cv.h2.x = __float2half(a);
                cv.h2.y = __float2half(bb);
                val = cv.u;
            }
            w2h[idx] = val;
        }
        return;
    }

    __shared__ unsigned int xs[6 * 10 * 84];      // 20160 B  [ch][copy*5+row][84]
    __shared__ unsigned short B_lds[6 * 64 * 8];  // 6144 B, frag-linear

    int b = blockIdx.x;
    int pr = b % 80, t = b / 80;

    // ---- stage B fragments (w1 -> bf16, frag-linear)
    for (int q = tid; q < 3072; q += 320) {
        int i = q & 7, ll = (q >> 3) & 63, ks = q >> 9;
        int oc = ll & 31;
        int kg = ks * 16 + ((ll >> 5) << 3) + i;
        float w = (oc < 30) ? w1[oc * 96 + kg] : 0.f;
        B_lds[q] = bfbits(w);
    }

    // ---- stage x tile: rows 2pr-2..2pr+2, cols -2..161, 6 ch, E+O copies
    if (tid < 30) {
        int ch = tid / 5, r = tid % 5;
        int sr = 2 * pr - 2 + r;
        float x0 = ((unsigned)sr < 160u) ? x[((t * 6 + ch) * 160 + sr) * 160] : 0.f;
        xs[(ch * 10 + r) * 84] = 0u;
        xs[(ch * 10 + 5 + r) * 84] = cvtpk(0.f, x0);
    }
    // main pairs: unit u = (ch,row)*40 + q; float4 = src cols 4q..4q+3
#pragma unroll
    for (int n = 0; n < 4; ++n) {
        int u = n * 320 + tid;
        if (u >= 1200) break;
        int q = u % 40, combo = u / 40;
        int ch = combo / 5, r = combo % 5;
        int sr = 2 * pr - 2 + r;
        const float* xp = x + ((t * 6 + ch) * 160 + sr) * 160;
        f32x4 f; f.x = 0.f; f.y = 0.f; f.z = 0.f; f.w = 0.f;
        bool inr = (unsigned)sr < 160u;
        if (inr) f = *(const f32x4u*)(xp + 4 * q);
        float nx = __shfl_down(f.x, 1);           // neighbor's col 4q+4
        if ((tid & 63) == 63 && q != 39)          // cross-wave neighbor
            nx = inr ? xp[4 * q + 4] : 0.f;
        if (q == 39) nx = 0.f;                    // col 160 is padding
        unsigned int e0 = cvtpk(f.x, f.y), e1 = cvtpk(f.z, f.w);
        unsigned int o0 = cvtpk(f.y, f.z), o1 = cvtpk(f.w, nx);
        unsigned int baseE = (unsigned)(ch * 10 + r) * 84 + 2 * q + 1;
        unsigned int baseO = (unsigned)(ch * 10 + 5 + r) * 84 + 2 * q + 1;
        xs[baseE] = e0; xs[baseE + 1] = e1;
        xs[baseO] = o0; xs[baseO + 1] = o1;
    }
    __syncthreads();

    int l = tid & 63, wv = tid >> 6;
    int m = l & 31, hi = l >> 5;
    int j = wv * 32 + m;
    int a = j >> 1, par = j & 1;

    bf8s bq[6];
#pragma unroll
    for (int ks = 0; ks < 6; ++ks)
        bq[ks] = *(const bf8s*)&B_lds[(ks * 64 + l) * 8];

    f32x16 acc0 = (f32x16)(0.0f);
    f32x16 acc1 = (f32x16)(0.0f);
    unsigned int bidx0 = (unsigned)(par * 5 + 2 * hi) * 84 + a;

#pragma unroll
    for (int ks = 0; ks < 6; ++ks) {
        unsigned int bidx = bidx0 + (unsigned)ks * 840;
        unsigned int r00 = xs[bidx],       r01 = xs[bidx + 1];
        unsigned int r10 = xs[bidx + 84],  r11 = xs[bidx + 85];
        unsigned int r20 = xs[bidx + 168], r21 = xs[bidx + 169];
        union { bf8s s; unsigned int u4[4]; } a0, a1;
        a0.u4[0] = r00; a0.u4[1] = r01; a0.u4[2] = r10; a0.u4[3] = r11;
        a1.u4[0] = r10; a1.u4[1] = r11; a1.u4[2] = r20; a1.u4[3] = r21;
        acc0 = __builtin_amdgcn_mfma_f32_32x32x16_bf16(a0.s, bq[ks], acc0, 0, 0, 0);
        acc1 = __builtin_amdgcn_mfma_f32_32x32x16_bf16(a1.s, bq[ks], acc1, 0, 0, 0);
    }

    // fire(>1) + pool2x2 + pack 30 oc bits -> 3 mask planes of 10 bits
    unsigned int mbase = (unsigned int)((t * 80 + pr) * 80 + wv * 16);
#pragma unroll
    for (int aa = 0; aa < 8; ++aa) {
        bool s = acc0[2 * aa] > 1.f || acc0[2 * aa + 1] > 1.f ||
                 acc1[2 * aa] > 1.f || acc1[2 * aa + 1] > 1.f;
        unsigned long long bal = __ballot(s);
        if (l < 6) {
            int h = l >> 1;
            unsigned int word = (l & 1) ? (unsigned int)(bal >> 32)
                                        : (unsigned int)bal;
            int pc = (aa & 1) + ((aa >> 1) << 2) + ((l & 1) << 1);
            mask1[h * MASK_PLANE + mbase + pc] = (word >> (10 * h)) & 0x3FFu;
        }
    }
}

// ---------------- sparse conv2(3x3) + fire(1.0) + pool3x3 -> pool2m ballot
// block: (t, ph, 9 pw-ninths) = 4860 blocks, 256 thr = 4 waves.
// fp16 oc-pair weights: lane l of oc-half h owns ocs h*128+2l, h*128+2l+1;
// one u32 load = 128 ocs. Wave (h = wv&1, grp = wv>>1): grp0 walks windows
// (pwA, pwA+1) fused; grp1 walks pwA+2 solo (dual-spike).
// v_pk_add_f16 accumulation, UNCONDITIONAL adds: exhausted masks yield
// channel 30 (ctz of the 0x40000000 sentinel) whose w2h rows are zero.
__global__ __launch_bounds__(256) void k_conv2(const unsigned int* __restrict__ mask1,
                                               const unsigned int* __restrict__ w2h,
                                               unsigned long long* __restrict__ pool2m,
                                               unsigned int* __restrict__ flags2) {
    __shared__ unsigned int m_lds[5 * 84];  // rows 3ph-2..3ph+2, cols -2..81

    int b = blockIdx.x;
    int ninth = b % 9;  b /= 9;
    int ph = b % 27;
    int t = b / 27;
    int tid = threadIdx.x;
    int l = tid & 63, wv = tid >> 6;
    int h = wv & 1, grp = wv >> 1;
    int r0 = 3 * ph - 2;
    int pwA = ninth * 3;

    for (int idx = tid; idx < 420; idx += 256) {
        int r = idx / 84, col = idx % 84;
        int gr = r0 + r, gc = col - 2;
        unsigned int v = 0;
        if ((unsigned)gr < 80u && (unsigned)gc < 80u) {
            int i2 = (t * 80 + gr) * 80 + gc;
            v = mask1[i2] | (mask1[MASK_PLANE + i2] << 10) |
                (mask1[2 * MASK_PLANE + i2] << 20);
        }
        m_lds[idx] = v;
    }
    __syncthreads();

    const unsigned int* wb = w2h + h * 64 + l;  // [ck][pl] stride 128
    unsigned long long* prow = pool2m + ((t * 27 + ph) * 27) * 4 + 2 * h;
    __half2 zh = bch2(0u);

    if (grp == 0) {
        // ---- pw pair (pwA, pwA+1): fused walk, unconditional pk_add ----
        int c0A = 3 * pwA, c0B = c0A + 3;
        unsigned int qA[25], qB[25];
#pragma unroll
        for (int dr = 0; dr < 5; ++dr)
#pragma unroll
            for (int ds = 0; ds < 5; ++ds) {
                qA[dr * 5 + ds] = m_lds[dr * 84 + c0A + ds];
                qB[dr * 5 + ds] = m_lds[dr * 84 + c0B + ds];
            }

        __half2 accA[3][3], accB[3][3];
#pragma unroll
        for (int i = 0; i < 3; ++i)
#pragma unroll
            for (int j = 0; j < 3; ++j) { accA[i][j] = zh; accB[i][j] = zh; }

#pragma unroll
        for (int dr = 0; dr < 5; ++dr) {
#pragma unroll
            for (int ds = 0; ds < 5; ++ds) {
                unsigned int mA = qA[dr * 5 + ds];
                unsigned int mB = qB[dr * 5 + ds];
                while (mA | mB) {  // wave-uniform
                    int cA = __builtin_ctz(mA | 0x40000000u);  // empty -> 30
                    int cB = __builtin_ctz(mB | 0x40000000u);
                    mA &= mA - 1;  // 0 stays 0
                    mB &= mB - 1;
                    const unsigned int* pA = wb + cA * 1152;  // c stride 9*128
                    const unsigned int* pB = wb + cB * 1152;
                    unsigned int uA[3][3], uB[3][3];
#pragma unroll
                    for (int i = 0; i < 3; ++i) {
                        if (dr - i < 0 || dr - i > 2) continue;
#pragma unroll
                        for (int j = 0; j < 3; ++j) {
                            if (ds - j < 0 || ds - j > 2) continue;
                            int off = ((dr - i) * 3 + (ds - j)) * 128;
                            uA[i][j] = pA[off];
                            uB[i][j] = pB[off];
                        }
                    }
#pragma unroll
                    for (int i = 0; i < 3; ++i) {
                        if (dr - i < 0 || dr - i > 2) continue;
#pragma unroll
                        for (int j = 0; j < 3; ++j) {
                            if (ds - j < 0 || ds - j > 2) continue;
                            accA[i][j] = __hadd2(accA[i][j], bch2(uA[i][j]));
                            accB[i][j] = __hadd2(accB[i][j], bch2(uB[i][j]));
                        }
                    }
                }
            }
        }

        bool sA0 = false, sA1 = false, sB0 = false, sB1 = false;
#pragma unroll
        for (int i = 0; i < 3; ++i)
#pragma unroll
            for (int j = 0; j < 3; ++j) {
                sA0 = sA0 || (__low2float(accA[i][j])  > 1.f);
                sA1 = sA1 || (__high2float(accA[i][j]) > 1.f);
                sB0 = sB0 || (__low2float(accB[i][j])  > 1.f);
                sB1 = sB1 || (__high2float(accB[i][j]) > 1.f);
            }
        unsigned long long bA0 = __ballot(sA0), bA1 = __ballot(sA1);
        unsigned long long bB0 = __ballot(sB0), bB1 = __ballot(sB1);
        unsigned long long wA0 = expand32((unsigned int)bA0) |
                                 (expand32((unsigned int)bA1) << 1);
        unsigned long long wA1 = expand32((unsigned int)(bA0 >> 32)) |
                                 (expand32((unsigned int)(bA1 >> 32)) << 1);
        unsigned long long wB0 = expand32((unsigned int)bB0) |
                                 (expand32((unsigned int)bB1) << 1);
        unsigned long long wB1 = expand32((unsigned int)(bB0 >> 32)) |
                                 (expand32((unsigned int)(bB1 >> 32)) << 1);
        if (l == 0) {
            prow[pwA * 4]           = wA0;
            prow[pwA * 4 + 1]       = wA1;
            prow[(pwA + 1) * 4]     = wB0;
            prow[(pwA + 1) * 4 + 1] = wB1;
        }
        if ((wA0 | wA1 | wB0 | wB1) && l == 0)
            flags2[t * 27 + ph] = 1u;  // same-value multi-writer
    } else {
        // ---- solo pw (pwA+2), dual-spike walk, unconditional pk_add ----
        int pw = pwA + 2;
        int c0 = 3 * pw;
        unsigned int q[25];
#pragma unroll
        for (int dr = 0; dr < 5; ++dr)
#pragma unroll
            for (int ds = 0; ds < 5; ++ds)
                q[dr * 5 + ds] = m_lds[dr * 84 + c0 + ds];

        __half2 acc[3][3];
#pragma unroll
        for (int i = 0; i < 3; ++i)
#pragma unroll
            for (int j = 0; j < 3; ++j) acc[i][j] = zh;

#pragma unroll
        for (int dr = 0; dr < 5; ++dr) {
#pragma unroll
            for (int ds = 0; ds < 5; ++ds) {
                unsigned int m = q[dr * 5 + ds];
                while (m) {  // wave-uniform
                    int c1 = __builtin_ctz(m); m &= m - 1;
                    int c2 = m ? __builtin_ctz(m) : 30;  // empty -> zero row
                    m &= m - 1;  // 0 stays 0
                    const unsigned int* p1 = wb + c1 * 1152;
                    const unsigned int* p2 = wb + c2 * 1152;
                    unsigned int u1[3][3], u2[3][3];
#pragma unroll
                    for (int i = 0; i < 3; ++i) {
                        if (dr - i < 0 || dr - i > 2) continue;
#pragma unroll
                        for (int j = 0; j < 3; ++j) {
                            if (ds - j < 0 || ds - j > 2) continue;
                            int off = ((dr - i) * 3 + (ds - j)) * 128;
                            u1[i][j] = p1[off];
                            u2[i][j] = p2[off];
                        }
                    }
#pragma unroll
                    for (int i = 0; i < 3; ++i) {
                        if (dr - i < 0 || dr - i > 2) continue;
#pragma unroll
                        for (int j = 0; j < 3; ++j) {
                            if (ds - j < 0 || ds - j > 2) continue;
                            acc[i][j] = __hadd2(acc[i][j], bch2(u1[i][j]));
                            acc[i][j] = __hadd2(acc[i][j], bch2(u2[i][j]));
                        }
                    }
                }
            }
        }

        bool s0 = false, s1 = false;
#pragma unroll
        for (int i = 0; i < 3; ++i)
#pragma unroll
            for (int j = 0; j < 3; ++j) {
                s0 = s0 || (__low2float(acc[i][j])  > 1.f);
                s1 = s1 || (__high2float(acc[i][j]) > 1.f);
            }
        unsigned long long b0 = __ballot(s0), b1 = __ballot(s1);
        unsigned long long w0 = expand32((unsigned int)b0) |
                                (expand32((unsigned int)b1) << 1);
        unsigned long long w1 = expand32((unsigned int)(b0 >> 32)) |
                                (expand32((unsigned int)(b1 >> 32)) << 1);
        if (l == 0) {
            prow[pw * 4]     = w0;
            prow[pw * 4 + 1] = w1;
        }
        if ((w0 | w1) && l == 0) flags2[t * 27 + ph] = 1u;
    }
}

// ---------------- conv3(3x3) + fire(25.0) -> out [spk|pot] (20,200,29,29) x2
__global__ __launch_bounds__(320) void k_conv3(const unsigned long long* __restrict__ pool2m,
                                               const float* __restrict__ w3,
                                               float* __restrict__ out,
                                               const unsigned int* __restrict__ flags2) {
    __shared__ float w_lds[25 * 9 * 40];   // 9000 floats, [ck_local][ocl]
    __shared__ float in_lds[25 * 4 * 34];  // 3400 floats, [cl][r][col]

    int b = blockIdx.x;
    int rb = b % 15;  b /= 15;
    int ocg = b % 5;  b /= 5;
    int t = b;
    int oc0 = ocg * 40;
    int r0 = 2 * rb;  // output rows r0, r0+1
    int tid = threadIdx.x;
    int ocl = tid % 40, ct = tid / 40;  // ct in [0,8)

    // whole-t union of flags (wave-uniform scalar loads)
    {
        unsigned int fT = 0;
        const unsigned int* fp = flags2 + t * 27;
#pragma unroll
        for (int r = 0; r < 27; ++r) fT |= fp[r];
        if (fT == 0) {
            float4 z; z.x = 0.f; z.y = 0.f; z.z = 0.f; z.w = 0.f;
            float4* o0 = (float4*)(out + (size_t)t * T_FLOATS);
            float4* o1 = (float4*)(out + OUT_HALF + (size_t)t * T_FLOATS);
            int s = ocg * 15 + rb;           // slice id 0..74
            int lo = s * 561;                // 75*561 = 42075 >= 42050
            int hi = lo + 561; if (hi > 42050) hi = 42050;
            for (int i = lo + tid; i < hi; i += 320) {
                o0[i] = z;
                o1[i] = z;
            }
            return;
        }
    }

    // receptive field: pool2 rows r0-2..r0+1
    {
        unsigned int f = 0;
        int rlo = r0 - 2; if (rlo < 0) rlo = 0;
        int rhi = r0 + 1; if (rhi > 26) rhi = 26;
        for (int r = rlo; r <= rhi; ++r) f |= flags2[t * 27 + r];
        if (f == 0) {
            int nrows = (r0 + 1 < 29) ? 2 : 1;
            int stride = 29 * nrows;
            int cnt = 40 * stride;
            for (int idx = tid; idx < cnt; idx += 320) {
                int o = idx / stride, rem = idx % stride;
                size_t base = (size_t)((t * 200 + oc0 + o) * 29 + r0) * 29 + rem;
                out[base] = 0.f;
                out[OUT_HALF + base] = 0.f;
            }
            return;
        }
    }

    float acc[2][4];
#pragma unroll
    for (int i = 0; i < 2; ++i)
#pragma unroll
        for (int j = 0; j < 4; ++j) acc[i][j] = 0.f;

    for (int chn = 0; chn < 10; ++chn) {  // channel chunks of 25
        int cc0 = chn * 25;
        for (int idx = tid; idx < 25 * 9 * 40; idx += 320) {
            int o = idx % 40, ck = idx / 40;         // ck in [0,225)
            int ckg = cc0 * 9 + ck;                  // global (c,kh,kw) index
            w_lds[idx] = w3[(size_t)(oc0 + o) * 2250 + ckg];
        }
        for (int idx = tid; idx < 25 * 4 * 34; idx += 320) {
            int col = idx % 34;
            int rem = idx / 34;
            int r = rem & 3, cl = rem >> 2;
            int gr = r0 + r - 2, gc = col - 2;
            float v = 0.f;
            if ((unsigned)gr < 27u && (unsigned)gc < 27u) {
                int c = cc0 + cl;
                unsigned long long wbits =
                    pool2m[((t * 27 + gr) * 27 + gc) * 4 + (c >> 6)];
                v = (float)((wbits >> (c & 63)) & 1ull);
            }
            in_lds[idx] = v;
        }
        __syncthreads();

        for (int cl = 0; cl < 25; ++cl) {
            float in[4][6];
#pragma unroll
            for (int r = 0; r < 4; ++r)
#pragma unroll
                for (int j = 0; j < 6; ++j)
                    in[r][j] = in_lds[(cl * 4 + r) * 34 + ct * 4 + j];
            const float* wp = &w_lds[cl * 360 + ocl];
#pragma unroll
            for (int k = 0; k < 9; ++k) {
                float w = wp[k * 40];
                int kh = k / 3, kw = k % 3;
#pragma unroll
                for (int i = 0; i < 2; ++i)
#pragma unroll
                    for (int j = 0; j < 4; ++j)
                        acc[i][j] += in[i + kh][j + kw] * w;
            }
        }
        __syncthreads();
    }

    {
        int oc = oc0 + ocl;  // always < 200
#pragma unroll
        for (int i = 0; i < 2; ++i) {
            int r = r0 + i;
            if (r < 29) {
#pragma unroll
                for (int j = 0; j < 4; ++j) {
                    int col = ct * 4 + j;
                    if (col < 29) {
                        float pot = acc[i][j];
                        bool s = pot > 25.f;
                        size_t base = ((size_t)((t * 200 + oc) * 29 + r)) * 29 + col;
                        out[base] = s ? 1.f : 0.f;
                        out[OUT_HALF + base] = s ? pot : 0.f;
                    }
                }
            }
        }
    }
}

extern "C" void kernel_launch(void* const* d_in, const int* in_sizes, int n_in,
                              void* d_out, int out_size, void* d_ws, size_t ws_size,
                              hipStream_t stream) {
    const float* x  = (const float*)d_in[0];
    const float* w1 = (const float*)d_in[1];
    const float* w2 = (const float*)d_in[2];
    const float* w3 = (const float*)d_in[3];
    float* out = (float*)d_out;

    // workspace layout (bytes):
    //   mask1  u32: [0, 1,536,000)           3 planes x 20*80*80
    //   pool2m u64: [1,536,000, 2,002,560)   20*27*27*4 x 8B ballot words
    //   w2h    u32: [2,002,560, 2,145,408)   270x128 fp16 pairs + zero pad
    //   flags2    : [2,277,376, +2,160)      u32[20*27]
    unsigned int* mask1 = (unsigned int*)d_ws;
    unsigned long long* pool2m = (unsigned long long*)((char*)d_ws + 1536000);
    unsigned int* w2h = (unsigned int*)((char*)d_ws + 2002560);
    unsigned int* flags2 = (unsigned int*)((char*)d_ws + 2277376);

    // blocks 0..1599: conv1 (LDS-staged MFMA); 1600..1711: w2h pack + flags2
    k_conv1m<<<1712, 320, 0, stream>>>(x, w1, w2, w2h, mask1, flags2);
    k_conv2<<<20 * 27 * 9, 256, 0, stream>>>(mask1, w2h, pool2m, flags2);
    // MEASUREMENT: k_conv3 launched 3x (idempotent -- out rewritten with
    // identical values each run). conv3+gap ~= (total - 115.2)/2.
    k_conv3<<<20 * 5 * 15, 320, 0, stream>>>(pool2m, w3, out, flags2);
    k_conv3<<<20 * 5 * 15, 320, 0, stream>>>(pool2m, w3, out, flags2);
    k_conv3<<<20 * 5 * 15, 320, 0, stream>>>(pool2m, w3, out, flags2);
}

// Round 11
// 124.033 us; speedup vs baseline: 1.2705x; 1.0223x over previous
//
#include <hip/hip_runtime.h>
#include <hip/hip_bf16.h>
#include <hip/hip_fp16.h>

// deepSNN forward, layer_idx=3 path, element-sparse conv2.
// x:(20,6,160,160) w1:(30,6,4,4) w2:(250,30,3,3) w3:(200,250,3,3)
// pipeline: pad2->conv1->fire(1)->pool2x2 -> pad2->conv2->fire(1)->pool3x3
//           -> pad2->conv3->fire(25) -> out = [spk | pot] (2 x 20*200*29*29 fp32)
//
// r29: conv2 ninths merged 9->1. Measured books (r23/r27/r28 duplication):
// fill 44 (fixed) + conv1m 11 + conv2 21.2 + conv3 5.8 + ~33 harness memsets/
// graph overhead (gaps ~0). conv2's walk-targeted levers all small (-1/0/-5)
// and walk models underpredict 3-7x -> hypothesis: per-block fixed cost
// (420-word band staging + barrier + tails) duplicated 9x across ninths is
// the real cost. New conv2: 540 blocks (t,ph) x 512 thr = 8 waves = 2
// engines x (h, grp); band staged ONCE; engine e walks ninths e,e+2,..
// with the identical r26 pair/solo inner code. Walk work unchanged;
// staging+fixed costs /9. Bit-identical outputs (same arithmetic).
// r25/r26: conv2 v_pk_add_f16 + zero-sentinel (unconditional adds).
// r24: conv1m LDS-staged. r19: conv1 bf16 MFMA implicit GEMM.

#define OUT_HALF 3364000  // 20*200*29*29
#define MASK_PLANE 128000 // 20*80*80 (u32 elements per plane)
#define T_FLOATS 168200   // 200*29*29 floats per t per half

typedef float f32x16 __attribute__((ext_vector_type(16)));
typedef short bf8s __attribute__((ext_vector_type(8)));
typedef float f32x4 __attribute__((ext_vector_type(4)));
typedef f32x4 f32x4u __attribute__((aligned(4)));  // 4B-aligned vec4 load

// HW packed f32->bf16 RTE: dst.lo16 = bf16(a), dst.hi16 = bf16(b).
static __device__ __forceinline__ unsigned int cvtpk(float a, float b) {
    unsigned int r;
    asm("v_cvt_pk_bf16_f32 %0, %1, %2" : "=v"(r) : "v"(a), "v"(b));
    return r;
}
static __device__ __forceinline__ unsigned short bfbits(float a) {
    union { __hip_bfloat16 h; unsigned short u; } cv;
    cv.h = __float2bfloat16(a);
    return cv.u;
}
static __device__ __forceinline__ __half2 bch2(unsigned int u) {
    union { unsigned int u32; __half2 h2; } cv; cv.u32 = u;
    return cv.h2;
}
// interleave: bit k of v -> bit 2k
static __device__ __forceinline__ unsigned long long expand32(unsigned int v) {
    unsigned long long x = v;
    x = (x | (x << 16)) & 0x0000FFFF0000FFFFull;
    x = (x | (x << 8))  & 0x00FF00FF00FF00FFull;
    x = (x | (x << 4))  & 0x0F0F0F0F0F0F0F0Full;
    x = (x | (x << 2))  & 0x3333333333333333ull;
    x = (x | (x << 1))  & 0x5555555555555555ull;
    return x;
}

// ---------------- conv1 (bf16 MFMA, LDS-staged) + fire(1) + pool2x2 -> mask1
//                  blocks 0..1599: conv1 (t=b/80, pr=b%80), 320 thr, 5 waves
//                  blocks 1600..1711: w2h pack (+ zero sentinel pad) + flags2
// LDS xs[ch][copy][row][84] u32: row = local src row 0..4 (global 2pr-2+row),
//   copy0 (E) pair p = src cols (2p-2, 2p-1); copy1 (O) pair k = (2k-1, 2k).
//   OOB staged as 0. Wave wv = jblk: output rows 2pr (acc0), 2pr+1 (acc1),
//   cols j=32wv+m. Lane (m=l&31, hi=l>>5): A-frag rows local 2hi+{0,1,2},
//   cols j-2..j+1 = pairs a, a+1 of copy (j&1), a = j>>1.
// C/D: col(oc)=lane&31, row(j-idx)=(reg&3)+8*(reg>>2)+4*hi  [verified map]
__global__ __launch_bounds__(320) void k_conv1m(const float* __restrict__ x,
                                                const float* __restrict__ w1,
                                                const float* __restrict__ w2,
                                                unsigned int* __restrict__ w2h,
                                                unsigned int* __restrict__ mask1,
                                                unsigned int* __restrict__ flags2) {
    int tid = threadIdx.x;
    if (blockIdx.x >= 1600) {  // w2h[ck*128+pl] = pack(w2[2pl][ck], w2[2pl+1][ck])
        int tb = blockIdx.x - 1600;
        if (tb == 0)
            for (int i = tid; i < 540; i += 320) flags2[i] = 0u;
        int idx = tb * 320 + tid;  // < 112*320 = 35840
        if (idx < 35712) {         // [34560,35712) = zero sentinel region (c=30)
            unsigned int val = 0u;
            if (idx < 34560) {
                int ck = idx >> 7, pl = idx & 127;
                int oc0 = 2 * pl, oc1 = oc0 + 1;
                float a = (oc0 < 250) ? w2[oc0 * 270 + ck] : 0.f;
                float bb = (oc1 < 250) ? w2[oc1 * 270 + ck] : 0.f;
                union { __half2 h2; unsigned int u; } cv;
                cv.h2.x = __float2half(a);
                cv.h2.y = __float2half(bb);
                val = cv.u;
            }
            w2h[idx] = val;
        }
        return;
    }

    __shared__ unsigned int xs[6 * 10 * 84];      // 20160 B  [ch][copy*5+row][84]
    __shared__ unsigned short B_lds[6 * 64 * 8];  // 6144 B, frag-linear

    int b = blockIdx.x;
    int pr = b % 80, t = b / 80;

    // ---- stage B fragments (w1 -> bf16, frag-linear)
    for (int q = tid; q < 3072; q += 320) {
        int i = q & 7, ll = (q >> 3) & 63, ks = q >> 9;
        int oc = ll & 31;
        int kg = ks * 16 + ((ll >> 5) << 3) + i;
        float w = (oc < 30) ? w1[oc * 96 + kg] : 0.f;
        B_lds[q] = bfbits(w);
    }

    // ---- stage x tile: rows 2pr-2..2pr+2, cols -2..161, 6 ch, E+O copies
    if (tid < 30) {
        int ch = tid / 5, r = tid % 5;
        int sr = 2 * pr - 2 + r;
        float x0 = ((unsigned)sr < 160u) ? x[((t * 6 + ch) * 160 + sr) * 160] : 0.f;
        xs[(ch * 10 + r) * 84] = 0u;
        xs[(ch * 10 + 5 + r) * 84] = cvtpk(0.f, x0);
    }
    // main pairs: unit u = (ch,row)*40 + q; float4 = src cols 4q..4q+3
#pragma unroll
    for (int n = 0; n < 4; ++n) {
        int u = n * 320 + tid;
        if (u >= 1200) break;
        int q = u % 40, combo = u / 40;
        int ch = combo / 5, r = combo % 5;
        int sr = 2 * pr - 2 + r;
        const float* xp = x + ((t * 6 + ch) * 160 + sr) * 160;
        f32x4 f; f.x = 0.f; f.y = 0.f; f.z = 0.f; f.w = 0.f;
        bool inr = (unsigned)sr < 160u;
        if (inr) f = *(const f32x4u*)(xp + 4 * q);
        float nx = __shfl_down(f.x, 1);           // neighbor's col 4q+4
        if ((tid & 63) == 63 && q != 39)          // cross-wave neighbor
            nx = inr ? xp[4 * q + 4] : 0.f;
        if (q == 39) nx = 0.f;                    // col 160 is padding
        unsigned int e0 = cvtpk(f.x, f.y), e1 = cvtpk(f.z, f.w);
        unsigned int o0 = cvtpk(f.y, f.z), o1 = cvtpk(f.w, nx);
        unsigned int baseE = (unsigned)(ch * 10 + r) * 84 + 2 * q + 1;
        unsigned int baseO = (unsigned)(ch * 10 + 5 + r) * 84 + 2 * q + 1;
        xs[baseE] = e0; xs[baseE + 1] = e1;
        xs[baseO] = o0; xs[baseO + 1] = o1;
    }
    __syncthreads();

    int l = tid & 63, wv = tid >> 6;
    int m = l & 31, hi = l >> 5;
    int j = wv * 32 + m;
    int a = j >> 1, par = j & 1;

    bf8s bq[6];
#pragma unroll
    for (int ks = 0; ks < 6; ++ks)
        bq[ks] = *(const bf8s*)&B_lds[(ks * 64 + l) * 8];

    f32x16 acc0 = (f32x16)(0.0f);
    f32x16 acc1 = (f32x16)(0.0f);
    unsigned int bidx0 = (unsigned)(par * 5 + 2 * hi) * 84 + a;

#pragma unroll
    for (int ks = 0; ks < 6; ++ks) {
        unsigned int bidx = bidx0 + (unsigned)ks * 840;
        unsigned int r00 = xs[bidx],       r01 = xs[bidx + 1];
        unsigned int r10 = xs[bidx + 84],  r11 = xs[bidx + 85];
        unsigned int r20 = xs[bidx + 168], r21 = xs[bidx + 169];
        union { bf8s s; unsigned int u4[4]; } a0, a1;
        a0.u4[0] = r00; a0.u4[1] = r01; a0.u4[2] = r10; a0.u4[3] = r11;
        a1.u4[0] = r10; a1.u4[1] = r11; a1.u4[2] = r20; a1.u4[3] = r21;
        acc0 = __builtin_amdgcn_mfma_f32_32x32x16_bf16(a0.s, bq[ks], acc0, 0, 0, 0);
        acc1 = __builtin_amdgcn_mfma_f32_32x32x16_bf16(a1.s, bq[ks], acc1, 0, 0, 0);
    }

    // fire(>1) + pool2x2 + pack 30 oc bits -> 3 mask planes of 10 bits
    unsigned int mbase = (unsigned int)((t * 80 + pr) * 80 + wv * 16);
#pragma unroll
    for (int aa = 0; aa < 8; ++aa) {
        bool s = acc0[2 * aa] > 1.f || acc0[2 * aa + 1] > 1.f ||
                 acc1[2 * aa] > 1.f || acc1[2 * aa + 1] > 1.f;
        unsigned long long bal = __ballot(s);
        if (l < 6) {
            int h = l >> 1;
            unsigned int word = (l & 1) ? (unsigned int)(bal >> 32)
                                        : (unsigned int)bal;
            int pc = (aa & 1) + ((aa >> 1) << 2) + ((l & 1) << 1);
            mask1[h * MASK_PLANE + mbase + pc] = (word >> (10 * h)) & 0x3FFu;
        }
    }
}

// ---------------- sparse conv2(3x3) + fire(1.0) + pool3x3 -> pool2m ballot
// r29: one block per (t, ph) = 540 blocks x 512 thr = 8 waves.
// Wave wv: h = wv&1 (oc half), grp = (wv>>1)&1 (pair/solo), eng = wv>>2.
// Band (5 x 84 merged mask words) staged ONCE; engine e handles ninths
// e, e+2, .. ; per ninth the r26 inner code: grp0 = fused pair walk of
// (pwA, pwA+1), grp1 = solo dual-spike walk of pwA+2.
// fp16 oc-pair weights; v_pk_add_f16 accumulation; UNCONDITIONAL adds via
// the zero-weight sentinel (ctz of empty -> c=30 -> zeroed w2h rows).
__global__ __launch_bounds__(512) void k_conv2(const unsigned int* __restrict__ mask1,
                                               const unsigned int* __restrict__ w2h,
                                               unsigned long long* __restrict__ pool2m,
                                               unsigned int* __restrict__ flags2) {
    __shared__ unsigned int m_lds[5 * 84];  // rows 3ph-2..3ph+2, cols -2..81

    int b = blockIdx.x;
    int ph = b % 27;
    int t = b / 27;
    int tid = threadIdx.x;
    int l = tid & 63, wv = tid >> 6;
    int h = wv & 1, grp = (wv >> 1) & 1, eng = wv >> 2;
    int r0 = 3 * ph - 2;

    if (tid < 420) {
        int r = tid / 84, col = tid % 84;
        int gr = r0 + r, gc = col - 2;
        unsigned int v = 0;
        if ((unsigned)gr < 80u && (unsigned)gc < 80u) {
            int i2 = (t * 80 + gr) * 80 + gc;
            v = mask1[i2] | (mask1[MASK_PLANE + i2] << 10) |
                (mask1[2 * MASK_PLANE + i2] << 20);
        }
        m_lds[tid] = v;
    }
    __syncthreads();

    const unsigned int* wb = w2h + h * 64 + l;  // [ck][pl] stride 128
    unsigned long long* prow = pool2m + ((t * 27 + ph) * 27) * 4 + 2 * h;
    __half2 zh = bch2(0u);
    bool fired = false;

    for (int ninth = eng; ninth < 9; ninth += 2) {
        int pwA = ninth * 3;

        if (grp == 0) {
            // ---- pw pair (pwA, pwA+1): fused walk, unconditional pk_add ----
            int c0A = 3 * pwA, c0B = c0A + 3;
            unsigned int qA[25], qB[25];
#pragma unroll
            for (int dr = 0; dr < 5; ++dr)
#pragma unroll
                for (int ds = 0; ds < 5; ++ds) {
                    qA[dr * 5 + ds] = m_lds[dr * 84 + c0A + ds];
                    qB[dr * 5 + ds] = m_lds[dr * 84 + c0B + ds];
                }

            __half2 accA[3][3], accB[3][3];
#pragma unroll
            for (int i = 0; i < 3; ++i)
#pragma unroll
                for (int j = 0; j < 3; ++j) { accA[i][j] = zh; accB[i][j] = zh; }

#pragma unroll
            for (int dr = 0; dr < 5; ++dr) {
#pragma unroll
                for (int ds = 0; ds < 5; ++ds) {
                    unsigned int mA = qA[dr * 5 + ds];
                    unsigned int mB = qB[dr * 5 + ds];
                    while (mA | mB) {  // wave-uniform
                        int cA = __builtin_ctz(mA | 0x40000000u);  // empty -> 30
                        int cB = __builtin_ctz(mB | 0x40000000u);
                        mA &= mA - 1;  // 0 stays 0
                        mB &= mB - 1;
                        const unsigned int* pA = wb + cA * 1152;  // c stride 9*128
                        const unsigned int* pB = wb + cB * 1152;
                        unsigned int uA[3][3], uB[3][3];
#pragma unroll
                        for (int i = 0; i < 3; ++i) {
                            if (dr - i < 0 || dr - i > 2) continue;
#pragma unroll
                            for (int j = 0; j < 3; ++j) {
                                if (ds - j < 0 || ds - j > 2) continue;
                                int off = ((dr - i) * 3 + (ds - j)) * 128;
                                uA[i][j] = pA[off];
                                uB[i][j] = pB[off];
                            }
                        }
#pragma unroll
                        for (int i = 0; i < 3; ++i) {
                            if (dr - i < 0 || dr - i > 2) continue;
#pragma unroll
                            for (int j = 0; j < 3; ++j) {
                                if (ds - j < 0 || ds - j > 2) continue;
                                accA[i][j] = __hadd2(accA[i][j], bch2(uA[i][j]));
                                accB[i][j] = __hadd2(accB[i][j], bch2(uB[i][j]));
                            }
                        }
                    }
                }
            }

            bool sA0 = false, sA1 = false, sB0 = false, sB1 = false;
#pragma unroll
            for (int i = 0; i < 3; ++i)
#pragma unroll
                for (int j = 0; j < 3; ++j) {
                    sA0 = sA0 || (__low2float(accA[i][j])  > 1.f);
                    sA1 = sA1 || (__high2float(accA[i][j]) > 1.f);
                    sB0 = sB0 || (__low2float(accB[i][j])  > 1.f);
                    sB1 = sB1 || (__high2float(accB[i][j]) > 1.f);
                }
            unsigned long long bA0 = __ballot(sA0), bA1 = __ballot(sA1);
            unsigned long long bB0 = __ballot(sB0), bB1 = __ballot(sB1);
            unsigned long long wA0 = expand32((unsigned int)bA0) |
                                     (expand32((unsigned int)bA1) << 1);
            unsigned long long wA1 = expand32((unsigned int)(bA0 >> 32)) |
                                     (expand32((unsigned int)(bA1 >> 32)) << 1);
            unsigned long long wB0 = expand32((unsigned int)bB0) |
                                     (expand32((unsigned int)bB1) << 1);
            unsigned long long wB1 = expand32((unsigned int)(bB0 >> 32)) |
                                     (expand32((unsigned int)(bB1 >> 32)) << 1);
            if (l == 0) {
                prow[pwA * 4]           = wA0;
                prow[pwA * 4 + 1]       = wA1;
                prow[(pwA + 1) * 4]     = wB0;
                prow[(pwA + 1) * 4 + 1] = wB1;
            }
            fired = fired || ((wA0 | wA1 | wB0 | wB1) != 0ull);
        } else {
            // ---- solo pw (pwA+2), dual-spike walk, unconditional pk_add ----
            int pw = pwA + 2;
            int c0 = 3 * pw;
            unsigned int q[25];
#pragma unroll
            for (int dr = 0; dr < 5; ++dr)
#pragma unroll
                for (int ds = 0; ds < 5; ++ds)
                    q[dr * 5 + ds] = m_lds[dr * 84 + c0 + ds];

            __half2 acc[3][3];
#pragma unroll
            for (int i = 0; i < 3; ++i)
#pragma unroll
                for (int j = 0; j < 3; ++j) acc[i][j] = zh;

#pragma unroll
            for (int dr = 0; dr < 5; ++dr) {
#pragma unroll
                for (int ds = 0; ds < 5; ++ds) {
                    unsigned int m = q[dr * 5 + ds];
                    while (m) {  // wave-uniform
                        int c1 = __builtin_ctz(m); m &= m - 1;
                        int c2 = m ? __builtin_ctz(m) : 30;  // empty -> zero row
                        m &= m - 1;  // 0 stays 0
                        const unsigned int* p1 = wb + c1 * 1152;
                        const unsigned int* p2 = wb + c2 * 1152;
                        unsigned int u1[3][3], u2[3][3];
#pragma unroll
                        for (int i = 0; i < 3; ++i) {
                            if (dr - i < 0 || dr - i > 2) continue;
#pragma unroll
                            for (int j = 0; j < 3; ++j) {
                                if (ds - j < 0 || ds - j > 2) continue;
                                int off = ((dr - i) * 3 + (ds - j)) * 128;
                                u1[i][j] = p1[off];
                                u2[i][j] = p2[off];
                            }
                        }
#pragma unroll
                        for (int i = 0; i < 3; ++i) {
                            if (dr - i < 0 || dr - i > 2) continue;
#pragma unroll
                            for (int j = 0; j < 3; ++j) {
                                if (ds - j < 0 || ds - j > 2) continue;
                                acc[i][j] = __hadd2(acc[i][j], bch2(u1[i][j]));
                                acc[i][j] = __hadd2(acc[i][j], bch2(u2[i][j]));
                            }
                        }
                    }
                }
            }

            bool s0 = false, s1 = false;
#pragma unroll
            for (int i = 0; i < 3; ++i)
#pragma unroll
                for (int j = 0; j < 3; ++j) {
                    s0 = s0 || (__low2float(acc[i][j])  > 1.f);
                    s1 = s1 || (__high2float(acc[i][j]) > 1.f);
                }
            unsigned long long b0 = __ballot(s0), b1 = __ballot(s1);
            unsigned long long w0 = expand32((unsigned int)b0) |
                                    (expand32((unsigned int)b1) << 1);
            unsigned long long w1 = expand32((unsigned int)(b0 >> 32)) |
                                    (expand32((unsigned int)(b1 >> 32)) << 1);
            if (l == 0) {
                prow[pw * 4]     = w0;
                prow[pw * 4 + 1] = w1;
            }
            fired = fired || ((w0 | w1) != 0ull);
        }
    }

    if (fired && l == 0) flags2[t * 27 + ph] = 1u;  // same-value multi-writer
}

// ---------------- conv3(3x3) + fire(25.0) -> out [spk|pot] (20,200,29,29) x2
__global__ __launch_bounds__(320) void k_conv3(const unsigned long long* __restrict__ pool2m,
                                               const float* __restrict__ w3,
                                               float* __restrict__ out,
                                               const unsigned int* __restrict__ flags2) {
    __shared__ float w_lds[25 * 9 * 40];   // 9000 floats, [ck_local][ocl]
    __shared__ float in_lds[25 * 4 * 34];  // 3400 floats, [cl][r][col]

    int b = blockIdx.x;
    int rb = b % 15;  b /= 15;
    int ocg = b % 5;  b /= 5;
    int t = b;
    int oc0 = ocg * 40;
    int r0 = 2 * rb;  // output rows r0, r0+1
    int tid = threadIdx.x;
    int ocl = tid % 40, ct = tid / 40;  // ct in [0,8)

    // whole-t union of flags (wave-uniform scalar loads)
    {
        unsigned int fT = 0;
        const unsigned int* fp = flags2 + t * 27;
#pragma unroll
        for (int r = 0; r < 27; ++r) fT |= fp[r];
        if (fT == 0) {
            float4 z; z.x = 0.f; z.y = 0.f; z.z = 0.f; z.w = 0.f;
            float4* o0 = (float4*)(out + (size_t)t * T_FLOATS);
            float4* o1 = (float4*)(out + OUT_HALF + (size_t)t * T_FLOATS);
            int s = ocg * 15 + rb;           // slice id 0..74
            int lo = s * 561;                // 75*561 = 42075 >= 42050
            int hi = lo + 561; if (hi > 42050) hi = 42050;
            for (int i = lo + tid; i < hi; i += 320) {
                o0[i] = z;
                o1[i] = z;
            }
            return;
        }
    }

    // receptive field: pool2 rows r0-2..r0+1
    {
        unsigned int f = 0;
        int rlo = r0 - 2; if (rlo < 0) rlo = 0;
        int rhi = r0 + 1; if (rhi > 26) rhi = 26;
        for (int r = rlo; r <= rhi; ++r) f |= flags2[t * 27 + r];
        if (f == 0) {
            int nrows = (r0 + 1 < 29) ? 2 : 1;
            int stride = 29 * nrows;
            int cnt = 40 * stride;
            for (int idx = tid; idx < cnt; idx += 320) {
                int o = idx / stride, rem = idx % stride;
                size_t base = (size_t)((t * 200 + oc0 + o) * 29 + r0) * 29 + rem;
                out[base] = 0.f;
                out[OUT_HALF + base] = 0.f;
            }
            return;
        }
    }

    float acc[2][4];
#pragma unroll
    for (int i = 0; i < 2; ++i)
#pragma unroll
        for (int j = 0; j < 4; ++j) acc[i][j] = 0.f;

    for (int chn = 0; chn < 10; ++chn) {  // channel chunks of 25
        int cc0 = chn * 25;
        for (int idx = tid; idx < 25 * 9 * 40; idx += 320) {
            int o = idx % 40, ck = idx / 40;         // ck in [0,225)
            int ckg = cc0 * 9 + ck;                  // global (c,kh,kw) index
            w_lds[idx] = w3[(size_t)(oc0 + o) * 2250 + ckg];
        }
        for (int idx = tid; idx < 25 * 4 * 34; idx += 320) {
            int col = idx % 34;
            int rem = idx / 34;
            int r = rem & 3, cl = rem >> 2;
            int gr = r0 + r - 2, gc = col - 2;
            float v = 0.f;
            if ((unsigned)gr < 27u && (unsigned)gc < 27u) {
                int c = cc0 + cl;
                unsigned long long wbits =
                    pool2m[((t * 27 + gr) * 27 + gc) * 4 + (c >> 6)];
                v = (float)((wbits >> (c & 63)) & 1ull);
            }
            in_lds[idx] = v;
        }
        __syncthreads();

        for (int cl = 0; cl < 25; ++cl) {
            float in[4][6];
#pragma unroll
            for (int r = 0; r < 4; ++r)
#pragma unroll
                for (int j = 0; j < 6; ++j)
                    in[r][j] = in_lds[(cl * 4 + r) * 34 + ct * 4 + j];
            const float* wp = &w_lds[cl * 360 + ocl];
#pragma unroll
            for (int k = 0; k < 9; ++k) {
                float w = wp[k * 40];
                int kh = k / 3, kw = k % 3;
#pragma unroll
                for (int i = 0; i < 2; ++i)
#pragma unroll
                    for (int j = 0; j < 4; ++j)
                        acc[i][j] += in[i + kh][j + kw] * w;
            }
        }
        __syncthreads();
    }

    {
        int oc = oc0 + ocl;  // always < 200
#pragma unroll
        for (int i = 0; i < 2; ++i) {
            int r = r0 + i;
            if (r < 29) {
#pragma unroll
                for (int j = 0; j < 4; ++j) {
                    int col = ct * 4 + j;
                    if (col < 29) {
                        float pot = acc[i][j];
                        bool s = pot > 25.f;
                        size_t base = ((size_t)((t * 200 + oc) * 29 + r)) * 29 + col;
                        out[base] = s ? 1.f : 0.f;
                        out[OUT_HALF + base] = s ? pot : 0.f;
                    }
                }
            }
        }
    }
}

extern "C" void kernel_launch(void* const* d_in, const int* in_sizes, int n_in,
                              void* d_out, int out_size, void* d_ws, size_t ws_size,
                              hipStream_t stream) {
    const float* x  = (const float*)d_in[0];
    const float* w1 = (const float*)d_in[1];
    const float* w2 = (const float*)d_in[2];
    const float* w3 = (const float*)d_in[3];
    float* out = (float*)d_out;

    // workspace layout (bytes):
    //   mask1  u32: [0, 1,536,000)           3 planes x 20*80*80
    //   pool2m u64: [1,536,000, 2,002,560)   20*27*27*4 x 8B ballot words
    //   w2h    u32: [2,002,560, 2,145,408)   270x128 fp16 pairs + zero pad
    //   flags2    : [2,277,376, +2,160)      u32[20*27]
    unsigned int* mask1 = (unsigned int*)d_ws;
    unsigned long long* pool2m = (unsigned long long*)((char*)d_ws + 1536000);
    unsigned int* w2h = (unsigned int*)((char*)d_ws + 2002560);
    unsigned int* flags2 = (unsigned int*)((char*)d_ws + 2277376);

    // blocks 0..1599: conv1 (LDS-staged MFMA); 1600..1711: w2h pack + flags2
    k_conv1m<<<1712, 320, 0, stream>>>(x, w1, w2, w2h, mask1, flags2);
    // conv2: one block per (t, ph); band staged once, 9 ninths walked
    k_conv2<<<20 * 27, 512, 0, stream>>>(mask1, w2h, pool2m, flags2);
    k_conv3<<<20 * 5 * 15, 320, 0, stream>>>(pool2m, w3, out, flags2);
}

// Round 12
// 117.047 us; speedup vs baseline: 1.3463x; 1.0597x over previous
//
#include <hip/hip_runtime.h>
#include <hip/hip_bf16.h>
#include <hip/hip_fp16.h>

// deepSNN forward, layer_idx=3 path, element-sparse conv2.
// x:(20,6,160,160) w1:(30,6,4,4) w2:(250,30,3,3) w3:(200,250,3,3)
// pipeline: pad2->conv1->fire(1)->pool2x2 -> pad2->conv2->fire(1)->pool3x3
//           -> pad2->conv3->fire(25) -> out = [spk | pot] (2 x 20*200*29*29 fp32)
//
// r30: conv2 REVERTED to the r26 4860-block form (r29's 9->1 ninth merge
// regressed +8.8us: the walk is latency-bound and lives on TLP -- 19440
// waves >> 4320; conv2 structure is now frozen at its measured optimum,
// 21.2us). conv1m experiment: block = (t, pr-PAIR) = 800 blocks x 320 thr;
// stage 7 source rows once (vs 2x5 across two blocks, 60% overlap) + B
// once; each wave runs two sequential passes (pool rows 2q, 2q+1; same acc
// regs, LDS row offset +168) -> x-staging -32%, B-staging/fixed costs -50%,
// fragments bit-identical -> mask1 unchanged, absmax stays 0.0.
// Books (r23/r27/r28 3x-launch): fill 44 fixed + conv1m 11 + conv2 21.2 +
// conv3 5.8 + ~33 harness memset/graph overhead (gaps ~0).
// r25/r26: conv2 v_pk_add_f16 + zero-sentinel. r24: conv1m LDS-staged.

#define OUT_HALF 3364000  // 20*200*29*29
#define MASK_PLANE 128000 // 20*80*80 (u32 elements per plane)
#define T_FLOATS 168200   // 200*29*29 floats per t per half

typedef float f32x16 __attribute__((ext_vector_type(16)));
typedef short bf8s __attribute__((ext_vector_type(8)));
typedef float f32x4 __attribute__((ext_vector_type(4)));
typedef f32x4 f32x4u __attribute__((aligned(4)));  // 4B-aligned vec4 load

// HW packed f32->bf16 RTE: dst.lo16 = bf16(a), dst.hi16 = bf16(b).
static __device__ __forceinline__ unsigned int cvtpk(float a, float b) {
    unsigned int r;
    asm("v_cvt_pk_bf16_f32 %0, %1, %2" : "=v"(r) : "v"(a), "v"(b));
    return r;
}
static __device__ __forceinline__ unsigned short bfbits(float a) {
    union { __hip_bfloat16 h; unsigned short u; } cv;
    cv.h = __float2bfloat16(a);
    return cv.u;
}
static __device__ __forceinline__ __half2 bch2(unsigned int u) {
    union { unsigned int u32; __half2 h2; } cv; cv.u32 = u;
    return cv.h2;
}
// interleave: bit k of v -> bit 2k
static __device__ __forceinline__ unsigned long long expand32(unsigned int v) {
    unsigned long long x = v;
    x = (x | (x << 16)) & 0x0000FFFF0000FFFFull;
    x = (x | (x << 8))  & 0x00FF00FF00FF00FFull;
    x = (x | (x << 4))  & 0x0F0F0F0F0F0F0F0Full;
    x = (x | (x << 2))  & 0x3333333333333333ull;
    x = (x | (x << 1))  & 0x5555555555555555ull;
    return x;
}

// ---------------- conv1 (bf16 MFMA, LDS-staged, pr-pair) + fire + pool2x2
//                  blocks 0..799: conv1 (t=b/40, q=b%40 -> pool rows 2q,2q+1)
//                  blocks 800..911: w2h pack (+ zero sentinel pad) + flags2
// LDS xs[(ch*2+copy)*7 + r][84] u32: r = local src row 0..6 (global 4q-2+r),
//   copy0 (E) pair p = src cols (2p-2, 2p-1); copy1 (O) pair k = (2k-1, 2k).
//   OOB staged as 0. Wave wv = jblk; two passes (pass = pool row 2q+pass):
//   lane (m=l&31, hi=l>>5) reads local rows 2hi+2*pass+{0,1,2}, pairs a,a+1
//   of copy (j&1), a = j>>1, j = 32wv+m.
// C/D: col(oc)=lane&31, row(j-idx)=(reg&3)+8*(reg>>2)+4*hi  [verified map]
__global__ __launch_bounds__(320) void k_conv1m(const float* __restrict__ x,
                                                const float* __restrict__ w1,
                                                const float* __restrict__ w2,
                                                unsigned int* __restrict__ w2h,
                                                unsigned int* __restrict__ mask1,
                                                unsigned int* __restrict__ flags2) {
    int tid = threadIdx.x;
    if (blockIdx.x >= 800) {  // w2h[ck*128+pl] = pack(w2[2pl][ck], w2[2pl+1][ck])
        int tb = blockIdx.x - 800;
        if (tb == 0)
            for (int i = tid; i < 540; i += 320) flags2[i] = 0u;
        int idx = tb * 320 + tid;  // < 112*320 = 35840
        if (idx < 35712) {         // [34560,35712) = zero sentinel region (c=30)
            unsigned int val = 0u;
            if (idx < 34560) {
                int ck = idx >> 7, pl = idx & 127;
                int oc0 = 2 * pl, oc1 = oc0 + 1;
                float a = (oc0 < 250) ? w2[oc0 * 270 + ck] : 0.f;
                float bb = (oc1 < 250) ? w2[oc1 * 270 + ck] : 0.f;
                union { __half2 h2; unsigned int u; } cv;
                cv.h2.x = __float2half(a);
                cv.h2.y = __float2half(bb);
                val = cv.u;
            }
            w2h[idx] = val;
        }
        return;
    }

    __shared__ unsigned int xs[6 * 2 * 7 * 84];   // 28224 B  [(ch*2+copy)*7+r][84]
    __shared__ unsigned short B_lds[6 * 64 * 8];  // 6144 B, frag-linear

    int b = blockIdx.x;
    int q = b % 40, t = b / 40;   // pool rows 2q, 2q+1; src rows 4q-2..4q+4

    // ---- stage B fragments (w1 -> bf16, frag-linear)
    for (int qq = tid; qq < 3072; qq += 320) {
        int i = qq & 7, ll = (qq >> 3) & 63, ks = qq >> 9;
        int oc = ll & 31;
        int kg = ks * 16 + ((ll >> 5) << 3) + i;
        float w = (oc < 30) ? w1[oc * 96 + kg] : 0.f;
        B_lds[qq] = bfbits(w);
    }

    // ---- stage x tile: src rows 4q-2..4q+4 (7), cols -2..161, 6 ch, E+O
    if (tid < 42) {  // boundary pair 0 of each (ch, r)
        int ch = tid / 7, r = tid % 7;
        int sr = 4 * q - 2 + r;
        float x0 = ((unsigned)sr < 160u) ? x[((t * 6 + ch) * 160 + sr) * 160] : 0.f;
        xs[(ch * 14 + r) * 84] = 0u;
        xs[(ch * 14 + 7 + r) * 84] = cvtpk(0.f, x0);
    }
    // main pairs: unit u = (ch,r)*40 + q4; float4 = src cols 4q4..4q4+3
#pragma unroll
    for (int n = 0; n < 6; ++n) {
        int u = n * 320 + tid;
        if (u >= 1680) break;
        int q4 = u % 40, combo = u / 40;
        int ch = combo / 7, r = combo % 7;
        int sr = 4 * q - 2 + r;
        const float* xp = x + ((t * 6 + ch) * 160 + sr) * 160;
        f32x4 f; f.x = 0.f; f.y = 0.f; f.z = 0.f; f.w = 0.f;
        bool inr = (unsigned)sr < 160u;
        if (inr) f = *(const f32x4u*)(xp + 4 * q4);
        float nx = __shfl_down(f.x, 1);           // neighbor's col 4q4+4
        if ((tid & 63) == 63 && q4 != 39)         // cross-wave neighbor
            nx = inr ? xp[4 * q4 + 4] : 0.f;
        if (q4 == 39) nx = 0.f;                   // col 160 is padding
        unsigned int e0 = cvtpk(f.x, f.y), e1 = cvtpk(f.z, f.w);
        unsigned int o0 = cvtpk(f.y, f.z), o1 = cvtpk(f.w, nx);
        unsigned int baseE = (unsigned)(ch * 14 + r) * 84 + 2 * q4 + 1;
        unsigned int baseO = (unsigned)(ch * 14 + 7 + r) * 84 + 2 * q4 + 1;
        xs[baseE] = e0; xs[baseE + 1] = e1;
        xs[baseO] = o0; xs[baseO + 1] = o1;
    }
    __syncthreads();

    int l = tid & 63, wv = tid >> 6;
    int m = l & 31, hi = l >> 5;
    int j = wv * 32 + m;
    int a = j >> 1, par = j & 1;

    bf8s bq[6];
#pragma unroll
    for (int ks = 0; ks < 6; ++ks)
        bq[ks] = *(const bf8s*)&B_lds[(ks * 64 + l) * 8];

#pragma unroll
    for (int pass = 0; pass < 2; ++pass) {
        f32x16 acc0 = (f32x16)(0.0f);
        f32x16 acc1 = (f32x16)(0.0f);
        unsigned int bidx0 =
            (unsigned)(par * 7 + 2 * hi + 2 * pass) * 84 + a;

#pragma unroll
        for (int ks = 0; ks < 6; ++ks) {
            unsigned int bidx = bidx0 + (unsigned)ks * 1176;  // ch stride 14*84
            unsigned int r00 = xs[bidx],       r01 = xs[bidx + 1];
            unsigned int r10 = xs[bidx + 84],  r11 = xs[bidx + 85];
            unsigned int r20 = xs[bidx + 168], r21 = xs[bidx + 169];
            union { bf8s s; unsigned int u4[4]; } a0, a1;
            a0.u4[0] = r00; a0.u4[1] = r01; a0.u4[2] = r10; a0.u4[3] = r11;
            a1.u4[0] = r10; a1.u4[1] = r11; a1.u4[2] = r20; a1.u4[3] = r21;
            acc0 = __builtin_amdgcn_mfma_f32_32x32x16_bf16(a0.s, bq[ks], acc0, 0, 0, 0);
            acc1 = __builtin_amdgcn_mfma_f32_32x32x16_bf16(a1.s, bq[ks], acc1, 0, 0, 0);
        }

        // fire(>1) + pool2x2 + pack 30 oc bits -> 3 mask planes of 10 bits
        int pr = 2 * q + pass;
        unsigned int mbase = (unsigned int)((t * 80 + pr) * 80 + wv * 16);
#pragma unroll
        for (int aa = 0; aa < 8; ++aa) {
            bool s = acc0[2 * aa] > 1.f || acc0[2 * aa + 1] > 1.f ||
                     acc1[2 * aa] > 1.f || acc1[2 * aa + 1] > 1.f;
            unsigned long long bal = __ballot(s);
            if (l < 6) {
                int h = l >> 1;
                unsigned int word = (l & 1) ? (unsigned int)(bal >> 32)
                                            : (unsigned int)bal;
                int pc = (aa & 1) + ((aa >> 1) << 2) + ((l & 1) << 1);
                mask1[h * MASK_PLANE + mbase + pc] = (word >> (10 * h)) & 0x3FFu;
            }
        }
    }
}

// ---------------- sparse conv2(3x3) + fire(1.0) + pool3x3 -> pool2m ballot
// r26 form (frozen): block (t, ph, 9 pw-ninths) = 4860 blocks, 256 thr.
// fp16 oc-pair weights: lane l of oc-half h owns ocs h*128+2l, h*128+2l+1;
// one u32 load = 128 ocs. Wave (h = wv&1, grp = wv>>1): grp0 walks windows
// (pwA, pwA+1) fused; grp1 walks pwA+2 solo (dual-spike).
// v_pk_add_f16 accumulation, UNCONDITIONAL adds: exhausted masks yield
// channel 30 (ctz of the 0x40000000 sentinel) whose w2h rows are zero.
__global__ __launch_bounds__(256) void k_conv2(const unsigned int* __restrict__ mask1,
                                               const unsigned int* __restrict__ w2h,
                                               unsigned long long* __restrict__ pool2m,
                                               unsigned int* __restrict__ flags2) {
    __shared__ unsigned int m_lds[5 * 84];  // rows 3ph-2..3ph+2, cols -2..81

    int b = blockIdx.x;
    int ninth = b % 9;  b /= 9;
    int ph = b % 27;
    int t = b / 27;
    int tid = threadIdx.x;
    int l = tid & 63, wv = tid >> 6;
    int h = wv & 1, grp = wv >> 1;
    int r0 = 3 * ph - 2;
    int pwA = ninth * 3;

    for (int idx = tid; idx < 420; idx += 256) {
        int r = idx / 84, col = idx % 84;
        int gr = r0 + r, gc = col - 2;
        unsigned int v = 0;
        if ((unsigned)gr < 80u && (unsigned)gc < 80u) {
            int i2 = (t * 80 + gr) * 80 + gc;
            v = mask1[i2] | (mask1[MASK_PLANE + i2] << 10) |
                (mask1[2 * MASK_PLANE + i2] << 20);
        }
        m_lds[idx] = v;
    }
    __syncthreads();

    const unsigned int* wb = w2h + h * 64 + l;  // [ck][pl] stride 128
    unsigned long long* prow = pool2m + ((t * 27 + ph) * 27) * 4 + 2 * h;
    __half2 zh = bch2(0u);

    if (grp == 0) {
        // ---- pw pair (pwA, pwA+1): fused walk, unconditional pk_add ----
        int c0A = 3 * pwA, c0B = c0A + 3;
        unsigned int qA[25], qB[25];
#pragma unroll
        for (int dr = 0; dr < 5; ++dr)
#pragma unroll
            for (int ds = 0; ds < 5; ++ds) {
                qA[dr * 5 + ds] = m_lds[dr * 84 + c0A + ds];
                qB[dr * 5 + ds] = m_lds[dr * 84 + c0B + ds];
            }

        __half2 accA[3][3], accB[3][3];
#pragma unroll
        for (int i = 0; i < 3; ++i)
#pragma unroll
            for (int j = 0; j < 3; ++j) { accA[i][j] = zh; accB[i][j] = zh; }

#pragma unroll
        for (int dr = 0; dr < 5; ++dr) {
#pragma unroll
            for (int ds = 0; ds < 5; ++ds) {
                unsigned int mA = qA[dr * 5 + ds];
                unsigned int mB = qB[dr * 5 + ds];
                while (mA | mB) {  // wave-uniform
                    int cA = __builtin_ctz(mA | 0x40000000u);  // empty -> 30
                    int cB = __builtin_ctz(mB | 0x40000000u);
                    mA &= mA - 1;  // 0 stays 0
                    mB &= mB - 1;
                    const unsigned int* pA = wb + cA * 1152;  // c stride 9*128
                    const unsigned int* pB = wb + cB * 1152;
                    unsigned int uA[3][3], uB[3][3];
#pragma unroll
                    for (int i = 0; i < 3; ++i) {
                        if (dr - i < 0 || dr - i > 2) continue;
#pragma unroll
                        for (int j = 0; j < 3; ++j) {
                            if (ds - j < 0 || ds - j > 2) continue;
                            int off = ((dr - i) * 3 + (ds - j)) * 128;
                            uA[i][j] = pA[off];
                            uB[i][j] = pB[off];
                        }
                    }
#pragma unroll
                    for (int i = 0; i < 3; ++i) {
                        if (dr - i < 0 || dr - i > 2) continue;
#pragma unroll
                        for (int j = 0; j < 3; ++j) {
                            if (ds - j < 0 || ds - j > 2) continue;
                            accA[i][j] = __hadd2(accA[i][j], bch2(uA[i][j]));
                            accB[i][j] = __hadd2(accB[i][j], bch2(uB[i][j]));
                        }
                    }
                }
            }
        }

        bool sA0 = false, sA1 = false, sB0 = false, sB1 = false;
#pragma unroll
        for (int i = 0; i < 3; ++i)
#pragma unroll
            for (int j = 0; j < 3; ++j) {
                sA0 = sA0 || (__low2float(accA[i][j])  > 1.f);
                sA1 = sA1 || (__high2float(accA[i][j]) > 1.f);
                sB0 = sB0 || (__low2float(accB[i][j])  > 1.f);
                sB1 = sB1 || (__high2float(accB[i][j]) > 1.f);
            }
        unsigned long long bA0 = __ballot(sA0), bA1 = __ballot(sA1);
        unsigned long long bB0 = __ballot(sB0), bB1 = __ballot(sB1);
        unsigned long long wA0 = expand32((unsigned int)bA0) |
                                 (expand32((unsigned int)bA1) << 1);
        unsigned long long wA1 = expand32((unsigned int)(bA0 >> 32)) |
                                 (expand32((unsigned int)(bA1 >> 32)) << 1);
        unsigned long long wB0 = expand32((unsigned int)bB0) |
                                 (expand32((unsigned int)bB1) << 1);
        unsigned long long wB1 = expand32((unsigned int)(bB0 >> 32)) |
                                 (expand32((unsigned int)(bB1 >> 32)) << 1);
        if (l == 0) {
            prow[pwA * 4]           = wA0;
            prow[pwA * 4 + 1]       = wA1;
            prow[(pwA + 1) * 4]     = wB0;
            prow[(pwA + 1) * 4 + 1] = wB1;
        }
        if ((wA0 | wA1 | wB0 | wB1) && l == 0)
            flags2[t * 27 + ph] = 1u;  // same-value multi-writer
    } else {
        // ---- solo pw (pwA+2), dual-spike walk, unconditional pk_add ----
        int pw = pwA + 2;
        int c0 = 3 * pw;
        unsigned int q[25];
#pragma unroll
        for (int dr = 0; dr < 5; ++dr)
#pragma unroll
            for (int ds = 0; ds < 5; ++ds)
                q[dr * 5 + ds] = m_lds[dr * 84 + c0 + ds];

        __half2 acc[3][3];
#pragma unroll
        for (int i = 0; i < 3; ++i)
#pragma unroll
            for (int j = 0; j < 3; ++j) acc[i][j] = zh;

#pragma unroll
        for (int dr = 0; dr < 5; ++dr) {
#pragma unroll
            for (int ds = 0; ds < 5; ++ds) {
                unsigned int m = q[dr * 5 + ds];
                while (m) {  // wave-uniform
                    int c1 = __builtin_ctz(m); m &= m - 1;
                    int c2 = m ? __builtin_ctz(m) : 30;  // empty -> zero row
                    m &= m - 1;  // 0 stays 0
                    const unsigned int* p1 = wb + c1 * 1152;
                    const unsigned int* p2 = wb + c2 * 1152;
                    unsigned int u1[3][3], u2[3][3];
#pragma unroll
                    for (int i = 0; i < 3; ++i) {
                        if (dr - i < 0 || dr - i > 2) continue;
#pragma unroll
                        for (int j = 0; j < 3; ++j) {
                            if (ds - j < 0 || ds - j > 2) continue;
                            int off = ((dr - i) * 3 + (ds - j)) * 128;
                            u1[i][j] = p1[off];
                            u2[i][j] = p2[off];
                        }
                    }
#pragma unroll
                    for (int i = 0; i < 3; ++i) {
                        if (dr - i < 0 || dr - i > 2) continue;
#pragma unroll
                        for (int j = 0; j < 3; ++j) {
                            if (ds - j < 0 || ds - j > 2) continue;
                            acc[i][j] = __hadd2(acc[i][j], bch2(u1[i][j]));
                            acc[i][j] = __hadd2(acc[i][j], bch2(u2[i][j]));
                        }
                    }
                }
            }
        }

        bool s0 = false, s1 = false;
#pragma unroll
        for (int i = 0; i < 3; ++i)
#pragma unroll
            for (int j = 0; j < 3; ++j) {
                s0 = s0 || (__low2float(acc[i][j])  > 1.f);
                s1 = s1 || (__high2float(acc[i][j]) > 1.f);
            }
        unsigned long long b0 = __ballot(s0), b1 = __ballot(s1);
        unsigned long long w0 = expand32((unsigned int)b0) |
                                (expand32((unsigned int)b1) << 1);
        unsigned long long w1 = expand32((unsigned int)(b0 >> 32)) |
                                (expand32((unsigned int)(b1 >> 32)) << 1);
        if (l == 0) {
            prow[pw * 4]     = w0;
            prow[pw * 4 + 1] = w1;
        }
        if ((w0 | w1) && l == 0) flags2[t * 27 + ph] = 1u;
    }
}

// ---------------- conv3(3x3) + fire(25.0) -> out [spk|pot] (20,200,29,29) x2
__global__ __launch_bounds__(320) void k_conv3(const unsigned long long* __restrict__ pool2m,
                                               const float* __restrict__ w3,
                                               float* __restrict__ out,
                                               const unsigned int* __restrict__ flags2) {
    __shared__ float w_lds[25 * 9 * 40];   // 9000 floats, [ck_local][ocl]
    __shared__ float in_lds[25 * 4 * 34];  // 3400 floats, [cl][r][col]

    int b = blockIdx.x;
    int rb = b % 15;  b /= 15;
    int ocg = b % 5;  b /= 5;
    int t = b;
    int oc0 = ocg * 40;
    int r0 = 2 * rb;  // output rows r0, r0+1
    int tid = threadIdx.x;
    int ocl = tid % 40, ct = tid / 40;  // ct in [0,8)

    // whole-t union of flags (wave-uniform scalar loads)
    {
        unsigned int fT = 0;
        const unsigned int* fp = flags2 + t * 27;
#pragma unroll
        for (int r = 0; r < 27; ++r) fT |= fp[r];
        if (fT == 0) {
            float4 z; z.x = 0.f; z.y = 0.f; z.z = 0.f; z.w = 0.f;
            float4* o0 = (float4*)(out + (size_t)t * T_FLOATS);
            float4* o1 = (float4*)(out + OUT_HALF + (size_t)t * T_FLOATS);
            int s = ocg * 15 + rb;           // slice id 0..74
            int lo = s * 561;                // 75*561 = 42075 >= 42050
            int hi = lo + 561; if (hi > 42050) hi = 42050;
            for (int i = lo + tid; i < hi; i += 320) {
                o0[i] = z;
                o1[i] = z;
            }
            return;
        }
    }

    // receptive field: pool2 rows r0-2..r0+1
    {
        unsigned int f = 0;
        int rlo = r0 - 2; if (rlo < 0) rlo = 0;
        int rhi = r0 + 1; if (rhi > 26) rhi = 26;
        for (int r = rlo; r <= rhi; ++r) f |= flags2[t * 27 + r];
        if (f == 0) {
            int nrows = (r0 + 1 < 29) ? 2 : 1;
            int stride = 29 * nrows;
            int cnt = 40 * stride;
            for (int idx = tid; idx < cnt; idx += 320) {
                int o = idx / stride, rem = idx % stride;
                size_t base = (size_t)((t * 200 + oc0 + o) * 29 + r0) * 29 + rem;
                out[base] = 0.f;
                out[OUT_HALF + base] = 0.f;
            }
            return;
        }
    }

    float acc[2][4];
#pragma unroll
    for (int i = 0; i < 2; ++i)
#pragma unroll
        for (int j = 0; j < 4; ++j) acc[i][j] = 0.f;

    for (int chn = 0; chn < 10; ++chn) {  // channel chunks of 25
        int cc0 = chn * 25;
        for (int idx = tid; idx < 25 * 9 * 40; idx += 320) {
            int o = idx % 40, ck = idx / 40;         // ck in [0,225)
            int ckg = cc0 * 9 + ck;                  // global (c,kh,kw) index
            w_lds[idx] = w3[(size_t)(oc0 + o) * 2250 + ckg];
        }
        for (int idx = tid; idx < 25 * 4 * 34; idx += 320) {
            int col = idx % 34;
            int rem = idx / 34;
            int r = rem & 3, cl = rem >> 2;
            int gr = r0 + r - 2, gc = col - 2;
            float v = 0.f;
            if ((unsigned)gr < 27u && (unsigned)gc < 27u) {
                int c = cc0 + cl;
                unsigned long long wbits =
                    pool2m[((t * 27 + gr) * 27 + gc) * 4 + (c >> 6)];
                v = (float)((wbits >> (c & 63)) & 1ull);
            }
            in_lds[idx] = v;
        }
        __syncthreads();

        for (int cl = 0; cl < 25; ++cl) {
            float in[4][6];
#pragma unroll
            for (int r = 0; r < 4; ++r)
#pragma unroll
                for (int j = 0; j < 6; ++j)
                    in[r][j] = in_lds[(cl * 4 + r) * 34 + ct * 4 + j];
            const float* wp = &w_lds[cl * 360 + ocl];
#pragma unroll
            for (int k = 0; k < 9; ++k) {
                float w = wp[k * 40];
                int kh = k / 3, kw = k % 3;
#pragma unroll
                for (int i = 0; i < 2; ++i)
#pragma unroll
                    for (int j = 0; j < 4; ++j)
                        acc[i][j] += in[i + kh][j + kw] * w;
            }
        }
        __syncthreads();
    }

    {
        int oc = oc0 + ocl;  // always < 200
#pragma unroll
        for (int i = 0; i < 2; ++i) {
            int r = r0 + i;
            if (r < 29) {
#pragma unroll
                for (int j = 0; j < 4; ++j) {
                    int col = ct * 4 + j;
                    if (col < 29) {
                        float pot = acc[i][j];
                        bool s = pot > 25.f;
                        size_t base = ((size_t)((t * 200 + oc) * 29 + r)) * 29 + col;
                        out[base] = s ? 1.f : 0.f;
                        out[OUT_HALF + base] = s ? pot : 0.f;
                    }
                }
            }
        }
    }
}

extern "C" void kernel_launch(void* const* d_in, const int* in_sizes, int n_in,
                              void* d_out, int out_size, void* d_ws, size_t ws_size,
                              hipStream_t stream) {
    const float* x  = (const float*)d_in[0];
    const float* w1 = (const float*)d_in[1];
    const float* w2 = (const float*)d_in[2];
    const float* w3 = (const float*)d_in[3];
    float* out = (float*)d_out;

    // workspace layout (bytes):
    //   mask1  u32: [0, 1,536,000)           3 planes x 20*80*80
    //   pool2m u64: [1,536,000, 2,002,560)   20*27*27*4 x 8B ballot words
    //   w2h    u32: [2,002,560, 2,145,408)   270x128 fp16 pairs + zero pad
    //   flags2    : [2,277,376, +2,160)      u32[20*27]
    unsigned int* mask1 = (unsigned int*)d_ws;
    unsigned long long* pool2m = (unsigned long long*)((char*)d_ws + 1536000);
    unsigned int* w2h = (unsigned int*)((char*)d_ws + 2002560);
    unsigned int* flags2 = (unsigned int*)((char*)d_ws + 2277376);

    // blocks 0..799: conv1 (pr-pair, LDS-staged MFMA); 800..911: w2h + flags2
    k_conv1m<<<912, 320, 0, stream>>>(x, w1, w2, w2h, mask1, flags2);
    // conv2: r26 form, 4860 blocks (frozen at measured optimum)
    k_conv2<<<20 * 27 * 9, 256, 0, stream>>>(mask1, w2h, pool2m, flags2);
    k_conv3<<<20 * 5 * 15, 320, 0, stream>>>(pool2m, w3, out, flags2);
}

// Round 13
// 114.606 us; speedup vs baseline: 1.3750x; 1.0213x over previous
//
#include <hip/hip_runtime.h>
#include <hip/hip_bf16.h>
#include <hip/hip_fp16.h>

// deepSNN forward, layer_idx=3 path, element-sparse conv2.
// x:(20,6,160,160) w1:(30,6,4,4) w2:(250,30,3,3) w3:(200,250,3,3)
// pipeline: pad2->conv1->fire(1)->pool2x2 -> pad2->conv2->fire(1)->pool3x3
//           -> pad2->conv3->fire(25) -> out = [spk | pot] (2 x 20*200*29*29 fp32)
//
// r31: FINAL REVERT to the best measured configuration (r26, 115.2us).
// r30's conv1m pr-pair merge was neutral-to-negative (+1.8us): like r29's
// conv2 ninth-merge (+8.8us), consolidating blocks trades fixed cost for
// TLP at break-even or worse -- both kernels are latency-bound and live on
// wave supply. Session books (3x-duplication measurements):
//   fill ~44 (fixed) + harness memsets/graph ~33 (fixed, gaps ~0)
//   + conv1m 11 + conv2 21.2 + conv3 5.8  ~= 115us.
// Lever history: conv2 bytes/2 (-1), windows 3->2 (0), VALU/4 (-5),
// blocks/9 (+8.8), dense MFMA (+9.6); conv1m stage-once (-4.6), pr-pair
// (+1.8). Remaining kernel work (38us) is within ~2x of data floors with
// all cheap levers exhausted; 77us is harness-fixed. Practical floor.
// r26: conv2 v_pk_add_f16 + zero-sentinel. r24: conv1m LDS-staged.
// r19: conv1 bf16 MFMA implicit GEMM (v_mfma_f32_32x32x16_bf16).

#define OUT_HALF 3364000  // 20*200*29*29
#define MASK_PLANE 128000 // 20*80*80 (u32 elements per plane)
#define T_FLOATS 168200   // 200*29*29 floats per t per half

typedef float f32x16 __attribute__((ext_vector_type(16)));
typedef short bf8s __attribute__((ext_vector_type(8)));
typedef float f32x4 __attribute__((ext_vector_type(4)));
typedef f32x4 f32x4u __attribute__((aligned(4)));  // 4B-aligned vec4 load

// HW packed f32->bf16 RTE: dst.lo16 = bf16(a), dst.hi16 = bf16(b).
static __device__ __forceinline__ unsigned int cvtpk(float a, float b) {
    unsigned int r;
    asm("v_cvt_pk_bf16_f32 %0, %1, %2" : "=v"(r) : "v"(a), "v"(b));
    return r;
}
static __device__ __forceinline__ unsigned short bfbits(float a) {
    union { __hip_bfloat16 h; unsigned short u; } cv;
    cv.h = __float2bfloat16(a);
    return cv.u;
}
static __device__ __forceinline__ __half2 bch2(unsigned int u) {
    union { unsigned int u32; __half2 h2; } cv; cv.u32 = u;
    return cv.h2;
}
// interleave: bit k of v -> bit 2k
static __device__ __forceinline__ unsigned long long expand32(unsigned int v) {
    unsigned long long x = v;
    x = (x | (x << 16)) & 0x0000FFFF0000FFFFull;
    x = (x | (x << 8))  & 0x00FF00FF00FF00FFull;
    x = (x | (x << 4))  & 0x0F0F0F0F0F0F0F0Full;
    x = (x | (x << 2))  & 0x3333333333333333ull;
    x = (x | (x << 1))  & 0x5555555555555555ull;
    return x;
}

// ---------------- conv1 (bf16 MFMA, LDS-staged) + fire(1) + pool2x2 -> mask1
//                  blocks 0..1599: conv1 (t=b/80, pr=b%80), 320 thr, 5 waves
//                  blocks 1600..1711: w2h pack (+ zero sentinel pad) + flags2
// LDS xs[ch][copy][row][84] u32: row = local src row 0..4 (global 2pr-2+row),
//   copy0 (E) pair p = src cols (2p-2, 2p-1); copy1 (O) pair k = (2k-1, 2k).
//   OOB staged as 0. Wave wv = jblk: output rows 2pr (acc0), 2pr+1 (acc1),
//   cols j=32wv+m. Lane (m=l&31, hi=l>>5): A-frag rows local 2hi+{0,1,2},
//   cols j-2..j+1 = pairs a, a+1 of copy (j&1), a = j>>1.
// C/D: col(oc)=lane&31, row(j-idx)=(reg&3)+8*(reg>>2)+4*hi  [verified map]
__global__ __launch_bounds__(320) void k_conv1m(const float* __restrict__ x,
                                                const float* __restrict__ w1,
                                                const float* __restrict__ w2,
                                                unsigned int* __restrict__ w2h,
                                                unsigned int* __restrict__ mask1,
                                                unsigned int* __restrict__ flags2) {
    int tid = threadIdx.x;
    if (blockIdx.x >= 1600) {  // w2h[ck*128+pl] = pack(w2[2pl][ck], w2[2pl+1][ck])
        int tb = blockIdx.x - 1600;
        if (tb == 0)
            for (int i = tid; i < 540; i += 320) flags2[i] = 0u;
        int idx = tb * 320 + tid;  // < 112*320 = 35840
        if (idx < 35712) {         // [34560,35712) = zero sentinel region (c=30)
            unsigned int val = 0u;
            if (idx < 34560) {
                int ck = idx >> 7, pl = idx & 127;
                int oc0 = 2 * pl, oc1 = oc0 + 1;
                float a = (oc0 < 250) ? w2[oc0 * 270 + ck] : 0.f;
                float bb = (oc1 < 250) ? w2[oc1 * 270 + ck] : 0.f;
                union { __half2 h2; unsigned int u; } cv;
                cv.h2.x = __float2half(a);
                cv.h2.y = __float2half(bb);
                val = cv.u;
            }
            w2h[idx] = val;
        }
        return;
    }

    __shared__ unsigned int xs[6 * 10 * 84];      // 20160 B  [ch][copy*5+row][84]
    __shared__ unsigned short B_lds[6 * 64 * 8];  // 6144 B, frag-linear

    int b = blockIdx.x;
    int pr = b % 80, t = b / 80;

    // ---- stage B fragments (w1 -> bf16, frag-linear)
    for (int q = tid; q < 3072; q += 320) {
        int i = q & 7, ll = (q >> 3) & 63, ks = q >> 9;
        int oc = ll & 31;
        int kg = ks * 16 + ((ll >> 5) << 3) + i;
        float w = (oc < 30) ? w1[oc * 96 + kg] : 0.f;
        B_lds[q] = bfbits(w);
    }

    // ---- stage x tile: rows 2pr-2..2pr+2, cols -2..161, 6 ch, E+O copies
    if (tid < 30) {
        int ch = tid / 5, r = tid % 5;
        int sr = 2 * pr - 2 + r;
        float x0 = ((unsigned)sr < 160u) ? x[((t * 6 + ch) * 160 + sr) * 160] : 0.f;
        xs[(ch * 10 + r) * 84] = 0u;
        xs[(ch * 10 + 5 + r) * 84] = cvtpk(0.f, x0);
    }
    // main pairs: unit u = (ch,row)*40 + q; float4 = src cols 4q..4q+3
#pragma unroll
    for (int n = 0; n < 4; ++n) {
        int u = n * 320 + tid;
        if (u >= 1200) break;
        int q = u % 40, combo = u / 40;
        int ch = combo / 5, r = combo % 5;
        int sr = 2 * pr - 2 + r;
        const float* xp = x + ((t * 6 + ch) * 160 + sr) * 160;
        f32x4 f; f.x = 0.f; f.y = 0.f; f.z = 0.f; f.w = 0.f;
        bool inr = (unsigned)sr < 160u;
        if (inr) f = *(const f32x4u*)(xp + 4 * q);
        float nx = __shfl_down(f.x, 1);           // neighbor's col 4q+4
        if ((tid & 63) == 63 && q != 39)          // cross-wave neighbor
            nx = inr ? xp[4 * q + 4] : 0.f;
        if (q == 39) nx = 0.f;                    // col 160 is padding
        unsigned int e0 = cvtpk(f.x, f.y), e1 = cvtpk(f.z, f.w);
        unsigned int o0 = cvtpk(f.y, f.z), o1 = cvtpk(f.w, nx);
        unsigned int baseE = (unsigned)(ch * 10 + r) * 84 + 2 * q + 1;
        unsigned int baseO = (unsigned)(ch * 10 + 5 + r) * 84 + 2 * q + 1;
        xs[baseE] = e0; xs[baseE + 1] = e1;
        xs[baseO] = o0; xs[baseO + 1] = o1;
    }
    __syncthreads();

    int l = tid & 63, wv = tid >> 6;
    int m = l & 31, hi = l >> 5;
    int j = wv * 32 + m;
    int a = j >> 1, par = j & 1;

    bf8s bq[6];
#pragma unroll
    for (int ks = 0; ks < 6; ++ks)
        bq[ks] = *(const bf8s*)&B_lds[(ks * 64 + l) * 8];

    f32x16 acc0 = (f32x16)(0.0f);
    f32x16 acc1 = (f32x16)(0.0f);
    unsigned int bidx0 = (unsigned)(par * 5 + 2 * hi) * 84 + a;

#pragma unroll
    for (int ks = 0; ks < 6; ++ks) {
        unsigned int bidx = bidx0 + (unsigned)ks * 840;
        unsigned int r00 = xs[bidx],       r01 = xs[bidx + 1];
        unsigned int r10 = xs[bidx + 84],  r11 = xs[bidx + 85];
        unsigned int r20 = xs[bidx + 168], r21 = xs[bidx + 169];
        union { bf8s s; unsigned int u4[4]; } a0, a1;
        a0.u4[0] = r00; a0.u4[1] = r01; a0.u4[2] = r10; a0.u4[3] = r11;
        a1.u4[0] = r10; a1.u4[1] = r11; a1.u4[2] = r20; a1.u4[3] = r21;
        acc0 = __builtin_amdgcn_mfma_f32_32x32x16_bf16(a0.s, bq[ks], acc0, 0, 0, 0);
        acc1 = __builtin_amdgcn_mfma_f32_32x32x16_bf16(a1.s, bq[ks], acc1, 0, 0, 0);
    }

    // fire(>1) + pool2x2 + pack 30 oc bits -> 3 mask planes of 10 bits
    unsigned int mbase = (unsigned int)((t * 80 + pr) * 80 + wv * 16);
#pragma unroll
    for (int aa = 0; aa < 8; ++aa) {
        bool s = acc0[2 * aa] > 1.f || acc0[2 * aa + 1] > 1.f ||
                 acc1[2 * aa] > 1.f || acc1[2 * aa + 1] > 1.f;
        unsigned long long bal = __ballot(s);
        if (l < 6) {
            int h = l >> 1;
            unsigned int word = (l & 1) ? (unsigned int)(bal >> 32)
                                        : (unsigned int)bal;
            int pc = (aa & 1) + ((aa >> 1) << 2) + ((l & 1) << 1);
            mask1[h * MASK_PLANE + mbase + pc] = (word >> (10 * h)) & 0x3FFu;
        }
    }
}

// ---------------- sparse conv2(3x3) + fire(1.0) + pool3x3 -> pool2m ballot
// block: (t, ph, 9 pw-ninths) = 4860 blocks, 256 thr = 4 waves.
// fp16 oc-pair weights: lane l of oc-half h owns ocs h*128+2l, h*128+2l+1;
// one u32 load = 128 ocs. Wave (h = wv&1, grp = wv>>1): grp0 walks windows
// (pwA, pwA+1) fused; grp1 walks pwA+2 solo (dual-spike).
// v_pk_add_f16 accumulation, UNCONDITIONAL adds: exhausted masks yield
// channel 30 (ctz of the 0x40000000 sentinel) whose w2h rows are zero.
__global__ __launch_bounds__(256) void k_conv2(const unsigned int* __restrict__ mask1,
                                               const unsigned int* __restrict__ w2h,
                                               unsigned long long* __restrict__ pool2m,
                                               unsigned int* __restrict__ flags2) {
    __shared__ unsigned int m_lds[5 * 84];  // rows 3ph-2..3ph+2, cols -2..81

    int b = blockIdx.x;
    int ninth = b % 9;  b /= 9;
    int ph = b % 27;
    int t = b / 27;
    int tid = threadIdx.x;
    int l = tid & 63, wv = tid >> 6;
    int h = wv & 1, grp = wv >> 1;
    int r0 = 3 * ph - 2;
    int pwA = ninth * 3;

    for (int idx = tid; idx < 420; idx += 256) {
        int r = idx / 84, col = idx % 84;
        int gr = r0 + r, gc = col - 2;
        unsigned int v = 0;
        if ((unsigned)gr < 80u && (unsigned)gc < 80u) {
            int i2 = (t * 80 + gr) * 80 + gc;
            v = mask1[i2] | (mask1[MASK_PLANE + i2] << 10) |
                (mask1[2 * MASK_PLANE + i2] << 20);
        }
        m_lds[idx] = v;
    }
    __syncthreads();

    const unsigned int* wb = w2h + h * 64 + l;  // [ck][pl] stride 128
    unsigned long long* prow = pool2m + ((t * 27 + ph) * 27) * 4 + 2 * h;
    __half2 zh = bch2(0u);

    if (grp == 0) {
        // ---- pw pair (pwA, pwA+1): fused walk, unconditional pk_add ----
        int c0A = 3 * pwA, c0B = c0A + 3;
        unsigned int qA[25], qB[25];
#pragma unroll
        for (int dr = 0; dr < 5; ++dr)
#pragma unroll
            for (int ds = 0; ds < 5; ++ds) {
                qA[dr * 5 + ds] = m_lds[dr * 84 + c0A + ds];
                qB[dr * 5 + ds] = m_lds[dr * 84 + c0B + ds];
            }

        __half2 accA[3][3], accB[3][3];
#pragma unroll
        for (int i = 0; i < 3; ++i)
#pragma unroll
            for (int j = 0; j < 3; ++j) { accA[i][j] = zh; accB[i][j] = zh; }

#pragma unroll
        for (int dr = 0; dr < 5; ++dr) {
#pragma unroll
            for (int ds = 0; ds < 5; ++ds) {
                unsigned int mA = qA[dr * 5 + ds];
                unsigned int mB = qB[dr * 5 + ds];
                while (mA | mB) {  // wave-uniform
                    int cA = __builtin_ctz(mA | 0x40000000u);  // empty -> 30
                    int cB = __builtin_ctz(mB | 0x40000000u);
                    mA &= mA - 1;  // 0 stays 0
                    mB &= mB - 1;
                    const unsigned int* pA = wb + cA * 1152;  // c stride 9*128
                    const unsigned int* pB = wb + cB * 1152;
                    unsigned int uA[3][3], uB[3][3];
#pragma unroll
                    for (int i = 0; i < 3; ++i) {
                        if (dr - i < 0 || dr - i > 2) continue;
#pragma unroll
                        for (int j = 0; j < 3; ++j) {
                            if (ds - j < 0 || ds - j > 2) continue;
                            int off = ((dr - i) * 3 + (ds - j)) * 128;
                            uA[i][j] = pA[off];
                            uB[i][j] = pB[off];
                        }
                    }
#pragma unroll
                    for (int i = 0; i < 3; ++i) {
                        if (dr - i < 0 || dr - i > 2) continue;
#pragma unroll
                        for (int j = 0; j < 3; ++j) {
                            if (ds - j < 0 || ds - j > 2) continue;
                            accA[i][j] = __hadd2(accA[i][j], bch2(uA[i][j]));
                            accB[i][j] = __hadd2(accB[i][j], bch2(uB[i][j]));
                        }
                    }
                }
            }
        }

        bool sA0 = false, sA1 = false, sB0 = false, sB1 = false;
#pragma unroll
        for (int i = 0; i < 3; ++i)
#pragma unroll
            for (int j = 0; j < 3; ++j) {
                sA0 = sA0 || (__low2float(accA[i][j])  > 1.f);
                sA1 = sA1 || (__high2float(accA[i][j]) > 1.f);
                sB0 = sB0 || (__low2float(accB[i][j])  > 1.f);
                sB1 = sB1 || (__high2float(accB[i][j]) > 1.f);
            }
        unsigned long long bA0 = __ballot(sA0), bA1 = __ballot(sA1);
        unsigned long long bB0 = __ballot(sB0), bB1 = __ballot(sB1);
        unsigned long long wA0 = expand32((unsigned int)bA0) |
                                 (expand32((unsigned int)bA1) << 1);
        unsigned long long wA1 = expand32((unsigned int)(bA0 >> 32)) |
                                 (expand32((unsigned int)(bA1 >> 32)) << 1);
        unsigned long long wB0 = expand32((unsigned int)bB0) |
                                 (expand32((unsigned int)bB1) << 1);
        unsigned long long wB1 = expand32((unsigned int)(bB0 >> 32)) |
                                 (expand32((unsigned int)(bB1 >> 32)) << 1);
        if (l == 0) {
            prow[pwA * 4]           = wA0;
            prow[pwA * 4 + 1]       = wA1;
            prow[(pwA + 1) * 4]     = wB0;
            prow[(pwA + 1) * 4 + 1] = wB1;
        }
        if ((wA0 | wA1 | wB0 | wB1) && l == 0)
            flags2[t * 27 + ph] = 1u;  // same-value multi-writer
    } else {
        // ---- solo pw (pwA+2), dual-spike walk, unconditional pk_add ----
        int pw = pwA + 2;
        int c0 = 3 * pw;
        unsigned int q[25];
#pragma unroll
        for (int dr = 0; dr < 5; ++dr)
#pragma unroll
            for (int ds = 0; ds < 5; ++ds)
                q[dr * 5 + ds] = m_lds[dr * 84 + c0 + ds];

        __half2 acc[3][3];
#pragma unroll
        for (int i = 0; i < 3; ++i)
#pragma unroll
            for (int j = 0; j < 3; ++j) acc[i][j] = zh;

#pragma unroll
        for (int dr = 0; dr < 5; ++dr) {
#pragma unroll
            for (int ds = 0; ds < 5; ++ds) {
                unsigned int m = q[dr * 5 + ds];
                while (m) {  // wave-uniform
                    int c1 = __builtin_ctz(m); m &= m - 1;
                    int c2 = m ? __builtin_ctz(m) : 30;  // empty -> zero row
                    m &= m - 1;  // 0 stays 0
                    const unsigned int* p1 = wb + c1 * 1152;
                    const unsigned int* p2 = wb + c2 * 1152;
                    unsigned int u1[3][3], u2[3][3];
#pragma unroll
                    for (int i = 0; i < 3; ++i) {
                        if (dr - i < 0 || dr - i > 2) continue;
#pragma unroll
                        for (int j = 0; j < 3; ++j) {
                            if (ds - j < 0 || ds - j > 2) continue;
                            int off = ((dr - i) * 3 + (ds - j)) * 128;
                            u1[i][j] = p1[off];
                            u2[i][j] = p2[off];
                        }
                    }
#pragma unroll
                    for (int i = 0; i < 3; ++i) {
                        if (dr - i < 0 || dr - i > 2) continue;
#pragma unroll
                        for (int j = 0; j < 3; ++j) {
                            if (ds - j < 0 || ds - j > 2) continue;
                            acc[i][j] = __hadd2(acc[i][j], bch2(u1[i][j]));
                            acc[i][j] = __hadd2(acc[i][j], bch2(u2[i][j]));
                        }
                    }
                }
            }
        }

        bool s0 = false, s1 = false;
#pragma unroll
        for (int i = 0; i < 3; ++i)
#pragma unroll
            for (int j = 0; j < 3; ++j) {
                s0 = s0 || (__low2float(acc[i][j])  > 1.f);
                s1 = s1 || (__high2float(acc[i][j]) > 1.f);
            }
        unsigned long long b0 = __ballot(s0), b1 = __ballot(s1);
        unsigned long long w0 = expand32((unsigned int)b0) |
                                (expand32((unsigned int)b1) << 1);
        unsigned long long w1 = expand32((unsigned int)(b0 >> 32)) |
                                (expand32((unsigned int)(b1 >> 32)) << 1);
        if (l == 0) {
            prow[pw * 4]     = w0;
            prow[pw * 4 + 1] = w1;
        }
        if ((w0 | w1) && l == 0) flags2[t * 27 + ph] = 1u;
    }
}

// ---------------- conv3(3x3) + fire(25.0) -> out [spk|pot] (20,200,29,29) x2
__global__ __launch_bounds__(320) void k_conv3(const unsigned long long* __restrict__ pool2m,
                                               const float* __restrict__ w3,
                                               float* __restrict__ out,
                                               const unsigned int* __restrict__ flags2) {
    __shared__ float w_lds[25 * 9 * 40];   // 9000 floats, [ck_local][ocl]
    __shared__ float in_lds[25 * 4 * 34];  // 3400 floats, [cl][r][col]

    int b = blockIdx.x;
    int rb = b % 15;  b /= 15;
    int ocg = b % 5;  b /= 5;
    int t = b;
    int oc0 = ocg * 40;
    int r0 = 2 * rb;  // output rows r0, r0+1
    int tid = threadIdx.x;
    int ocl = tid % 40, ct = tid / 40;  // ct in [0,8)

    // whole-t union of flags (wave-uniform scalar loads)
    {
        unsigned int fT = 0;
        const unsigned int* fp = flags2 + t * 27;
#pragma unroll
        for (int r = 0; r < 27; ++r) fT |= fp[r];
        if (fT == 0) {
            float4 z; z.x = 0.f; z.y = 0.f; z.z = 0.f; z.w = 0.f;
            float4* o0 = (float4*)(out + (size_t)t * T_FLOATS);
            float4* o1 = (float4*)(out + OUT_HALF + (size_t)t * T_FLOATS);
            int s = ocg * 15 + rb;           // slice id 0..74
            int lo = s * 561;                // 75*561 = 42075 >= 42050
            int hi = lo + 561; if (hi > 42050) hi = 42050;
            for (int i = lo + tid; i < hi; i += 320) {
                o0[i] = z;
                o1[i] = z;
            }
            return;
        }
    }

    // receptive field: pool2 rows r0-2..r0+1
    {
        unsigned int f = 0;
        int rlo = r0 - 2; if (rlo < 0) rlo = 0;
        int rhi = r0 + 1; if (rhi > 26) rhi = 26;
        for (int r = rlo; r <= rhi; ++r) f |= flags2[t * 27 + r];
        if (f == 0) {
            int nrows = (r0 + 1 < 29) ? 2 : 1;
            int stride = 29 * nrows;
            int cnt = 40 * stride;
            for (int idx = tid; idx < cnt; idx += 320) {
                int o = idx / stride, rem = idx % stride;
                size_t base = (size_t)((t * 200 + oc0 + o) * 29 + r0) * 29 + rem;
                out[base] = 0.f;
                out[OUT_HALF + base] = 0.f;
            }
            return;
        }
    }

    float acc[2][4];
#pragma unroll
    for (int i = 0; i < 2; ++i)
#pragma unroll
        for (int j = 0; j < 4; ++j) acc[i][j] = 0.f;

    for (int chn = 0; chn < 10; ++chn) {  // channel chunks of 25
        int cc0 = chn * 25;
        for (int idx = tid; idx < 25 * 9 * 40; idx += 320) {
            int o = idx % 40, ck = idx / 40;         // ck in [0,225)
            int ckg = cc0 * 9 + ck;                  // global (c,kh,kw) index
            w_lds[idx] = w3[(size_t)(oc0 + o) * 2250 + ckg];
        }
        for (int idx = tid; idx < 25 * 4 * 34; idx += 320) {
            int col = idx % 34;
            int rem = idx / 34;
            int r = rem & 3, cl = rem >> 2;
            int gr = r0 + r - 2, gc = col - 2;
            float v = 0.f;
            if ((unsigned)gr < 27u && (unsigned)gc < 27u) {
                int c = cc0 + cl;
                unsigned long long wbits =
                    pool2m[((t * 27 + gr) * 27 + gc) * 4 + (c >> 6)];
                v = (float)((wbits >> (c & 63)) & 1ull);
            }
            in_lds[idx] = v;
        }
        __syncthreads();

        for (int cl = 0; cl < 25; ++cl) {
            float in[4][6];
#pragma unroll
            for (int r = 0; r < 4; ++r)
#pragma unroll
                for (int j = 0; j < 6; ++j)
                    in[r][j] = in_lds[(cl * 4 + r) * 34 + ct * 4 + j];
            const float* wp = &w_lds[cl * 360 + ocl];
#pragma unroll
            for (int k = 0; k < 9; ++k) {
                float w = wp[k * 40];
                int kh = k / 3, kw = k % 3;
#pragma unroll
                for (int i = 0; i < 2; ++i)
#pragma unroll
                    for (int j = 0; j < 4; ++j)
                        acc[i][j] += in[i + kh][j + kw] * w;
            }
        }
        __syncthreads();
    }

    {
        int oc = oc0 + ocl;  // always < 200
#pragma unroll
        for (int i = 0; i < 2; ++i) {
            int r = r0 + i;
            if (r < 29) {
#pragma unroll
                for (int j = 0; j < 4; ++j) {
                    int col = ct * 4 + j;
                    if (col < 29) {
                        float pot = acc[i][j];
                        bool s = pot > 25.f;
                        size_t base = ((size_t)((t * 200 + oc) * 29 + r)) * 29 + col;
                        out[base] = s ? 1.f : 0.f;
                        out[OUT_HALF + base] = s ? pot : 0.f;
                    }
                }
            }
        }
    }
}

extern "C" void kernel_launch(void* const* d_in, const int* in_sizes, int n_in,
                              void* d_out, int out_size, void* d_ws, size_t ws_size,
                              hipStream_t stream) {
    const float* x  = (const float*)d_in[0];
    const float* w1 = (const float*)d_in[1];
    const float* w2 = (const float*)d_in[2];
    const float* w3 = (const float*)d_in[3];
    float* out = (float*)d_out;

    // workspace layout (bytes):
    //   mask1  u32: [0, 1,536,000)           3 planes x 20*80*80
    //   pool2m u64: [1,536,000, 2,002,560)   20*27*27*4 x 8B ballot words
    //   w2h    u32: [2,002,560, 2,145,408)   270x128 fp16 pairs + zero pad
    //   flags2    : [2,277,376, +2,160)      u32[20*27]
    unsigned int* mask1 = (unsigned int*)d_ws;
    unsigned long long* pool2m = (unsigned long long*)((char*)d_ws + 1536000);
    unsigned int* w2h = (unsigned int*)((char*)d_ws + 2002560);
    unsigned int* flags2 = (unsigned int*)((char*)d_ws + 2277376);

    // blocks 0..1599: conv1 (LDS-staged MFMA); 1600..1711: w2h pack + flags2
    k_conv1m<<<1712, 320, 0, stream>>>(x, w1, w2, w2h, mask1, flags2);
    k_conv2<<<20 * 27 * 9, 256, 0, stream>>>(mask1, w2h, pool2m, flags2);
    k_conv3<<<20 * 5 * 15, 320, 0, stream>>>(pool2m, w3, out, flags2);
}